// Round 12
// baseline (340.481 us; speedup 1.0000x reference)
//
#include <hip/hip_runtime.h>
#include <hip/hip_bf16.h>
#include <hip/hip_fp16.h>

// Problem constants (verified against setup_inputs)
#define C_DIN 128
#define C_H 4
#define C_CH 64     // per-head channels (CHID == COUT == 64)
#define C_HC 256    // H * CH
#define C_S 32
#define ACH 32      // aggregation / fusion chunk (edges)
#define MBLK 64     // GEMM M-tile (rows per block)

typedef __attribute__((ext_vector_type(8))) _Float16 half8;
typedef __attribute__((ext_vector_type(4))) float f32x4;

__device__ __forceinline__ float lrelu(float x) { return x >= 0.f ? x : 0.2f * x; }

// reductions confined to 32-lane subgroup (offsets <=16 never cross halves)
__device__ __forceinline__ float sub_sum32(float v) {
#pragma unroll
    for (int off = 16; off > 0; off >>= 1) v += __shfl_xor(v, off);
    return v;
}

// ---------------- CSR build ----------------
__global__ void k_count(const int* __restrict__ dst, int* __restrict__ deg, int E) {
    int e = blockIdx.x * blockDim.x + threadIdx.x;
    if (e < E) atomicAdd(&deg[dst[e]], 1);
}

__global__ void k_scan(const int* __restrict__ deg, int* __restrict__ row_ptr,
                       int* __restrict__ cursor, int n) {
    __shared__ int part[1024];
    int t = threadIdx.x;
    const int C = (n + 1023) / 1024;
    int base = t * C;
    int s = 0;
    for (int k = 0; k < C; ++k) {
        int idx = base + k;
        if (idx < n) s += deg[idx];
    }
    part[t] = s;
    __syncthreads();
    for (int off = 1; off < 1024; off <<= 1) {
        int v = (t >= off) ? part[t - off] : 0;
        __syncthreads();
        part[t] += v;
        __syncthreads();
    }
    int run = (t == 0) ? 0 : part[t - 1];
    for (int k = 0; k < C; ++k) {
        int idx = base + k;
        if (idx < n) { row_ptr[idx] = run; cursor[idx] = run; run += deg[idx]; }
    }
    if (t == 1023) row_ptr[n] = run;
}

__global__ void k_scatter(const int* __restrict__ src, const int* __restrict__ dst,
                          int* __restrict__ cursor, int* __restrict__ adj_src, int E) {
    int e = blockIdx.x * blockDim.x + threadIdx.x;
    if (e < E) {
        int d = dst[e];
        int p = atomicAdd(&cursor[d], 1);
        adj_src[p] = src[e];
    }
}

// ---------------- layer 1 GEMM (MFMA fp16): h = x @ W1^T, fused a_s1/a_d1 ----------------
__global__ __launch_bounds__(256) void k_gemm1(
    const float* __restrict__ x, const float* __restrict__ W1,
    const float* __restrict__ att_s, const float* __restrict__ att_d,
    __half* __restrict__ hh_out, float* __restrict__ a_s, float* __restrict__ a_d, int n) {
    __shared__ __align__(16) _Float16 bs[4 * 16 * 64 * 8];  // 64 KB
    __shared__ __align__(16) _Float16 as_[4 * 4 * 64 * 8];  // 16 KB
    int t = threadIdx.x;
    int r0 = blockIdx.x * MBLK;
    {
        int c = t;
        const float4* wrow = (const float4*)(W1 + (size_t)c * C_DIN);
        int nt = c >> 4, cl = c & 15;
#pragma unroll
        for (int ch = 0; ch < 16; ++ch) {
            float4 f0 = wrow[ch * 2], f1 = wrow[ch * 2 + 1];
            int ks = ch >> 2, lg = ch & 3;
            _Float16* dst = &bs[(((ks * 16 + nt) * 64) + (lg * 16 + cl)) * 8];
            dst[0] = (_Float16)f0.x; dst[1] = (_Float16)f0.y;
            dst[2] = (_Float16)f0.z; dst[3] = (_Float16)f0.w;
            dst[4] = (_Float16)f1.x; dst[5] = (_Float16)f1.y;
            dst[6] = (_Float16)f1.z; dst[7] = (_Float16)f1.w;
        }
    }
    {
        int row = t >> 2, q = t & 3;
        int rr = r0 + row;
        int mt = row >> 4, rl = row & 15;
        const float4* xrow = (const float4*)(x + (size_t)rr * C_DIN);
#pragma unroll
        for (int cc = 0; cc < 4; ++cc) {
            int ch = q * 4 + cc;
            float4 f0 = make_float4(0, 0, 0, 0), f1 = make_float4(0, 0, 0, 0);
            if (rr < n) { f0 = xrow[ch * 2]; f1 = xrow[ch * 2 + 1]; }
            int ks = ch >> 2, lg = ch & 3;
            _Float16* dst = &as_[(((ks * 4 + mt) * 64) + (lg * 16 + rl)) * 8];
            dst[0] = (_Float16)f0.x; dst[1] = (_Float16)f0.y;
            dst[2] = (_Float16)f0.z; dst[3] = (_Float16)f0.w;
            dst[4] = (_Float16)f1.x; dst[5] = (_Float16)f1.y;
            dst[6] = (_Float16)f1.z; dst[7] = (_Float16)f1.w;
        }
    }
    __syncthreads();
    int w = t >> 6, l = t & 63;
    f32x4 acc[4][4];
#pragma unroll
    for (int mt = 0; mt < 4; ++mt)
#pragma unroll
        for (int nt = 0; nt < 4; ++nt) acc[mt][nt] = (f32x4){0.f, 0.f, 0.f, 0.f};
#pragma unroll
    for (int ks = 0; ks < 4; ++ks) {
        half8 af[4], bf[4];
#pragma unroll
        for (int mt = 0; mt < 4; ++mt)
            af[mt] = *(const half8*)&as_[(((ks * 4 + mt) * 64) + l) * 8];
#pragma unroll
        for (int nt = 0; nt < 4; ++nt)
            bf[nt] = *(const half8*)&bs[(((ks * 16 + (w * 4 + nt)) * 64) + l) * 8];
#pragma unroll
        for (int mt = 0; mt < 4; ++mt)
#pragma unroll
            for (int nt = 0; nt < 4; ++nt)
                acc[mt][nt] = __builtin_amdgcn_mfma_f32_16x16x32_f16(af[mt], bf[nt],
                                                                     acc[mt][nt], 0, 0, 0);
    }
    int cl = l & 15, rg = l >> 4;
    float atv_s[4], atv_d[4];
#pragma unroll
    for (int nt = 0; nt < 4; ++nt) {
        atv_s[nt] = att_s[w * 64 + nt * 16 + cl];
        atv_d[nt] = att_d[w * 64 + nt * 16 + cl];
    }
#pragma unroll
    for (int mt = 0; mt < 4; ++mt) {
#pragma unroll
        for (int r = 0; r < 4; ++r) {
            int rr = r0 + mt * 16 + rg * 4 + r;
            float vs = 0.f, vd = 0.f;
#pragma unroll
            for (int nt = 0; nt < 4; ++nt) {
                float v = acc[mt][nt][r];
                vs += atv_s[nt] * v;
                vd += atv_d[nt] * v;
                if (rr < n)
                    hh_out[(size_t)rr * C_HC + w * 64 + nt * 16 + cl] = __float2half(v);
            }
#pragma unroll
            for (int off = 1; off < 16; off <<= 1) {
                vs += __shfl_xor(vs, off);
                vd += __shfl_xor(vd, off);
            }
            if (cl == 0 && rr < n) { a_s[rr * C_H + w] = vs; a_d[rr * C_H + w] = vd; }
        }
    }
}

// ---------------- layer 1 aggregation: single pass, unnormalized exp ----------------
__global__ void k_layer1(const int* __restrict__ row_ptr, const int* __restrict__ adj_src,
                         const __half* __restrict__ hhlf, const float* __restrict__ a_s,
                         const float* __restrict__ a_d, const float* __restrict__ bias1,
                         float* __restrict__ h1) {
    int d = blockIdx.x;
    int t = threadIdx.x, hh = t >> 5, cp = t & 31;
    int beg = row_ptr[d], end = row_ptr[d + 1];
    float adh = a_d[d * C_H + hh];
    float p_self = expf(lrelu(a_s[d * C_H + hh] + adh));
    __shared__ float alpha_l[C_H][ACH];
    __shared__ int src_l[ACH];
    const __half2* selfrow = (const __half2*)(hhlf + (size_t)d * C_HC + hh * 64);
    float2 sv = __half22float2(selfrow[cp]);
    float accx = p_self * sv.x, accy = p_self * sv.y;
    float s_part = (cp == 0) ? p_self : 0.f;
    for (int cbeg = beg; cbeg < end; cbeg += ACH) {
        int cn = min(end - cbeg, ACH);
        __syncthreads();
        if (cp < cn) {
            int s = adj_src[cbeg + cp];
            if (hh == 0) src_l[cp] = s;
            float p = expf(lrelu(a_s[s * C_H + hh] + adh));
            alpha_l[hh][cp] = p;
            s_part += p;
        }
        __syncthreads();
        for (int i = 0; i < cn; ++i) {
            int s = src_l[i];
            float a = alpha_l[hh][i];
            float2 v = __half22float2(
                *(const __half2*)(hhlf + (size_t)s * C_HC + hh * 64 + cp * 2));
            accx += a * v.x;
            accy += a * v.y;
        }
    }
    float s = sub_sum32(s_part);
    float inv = 1.f / (s + 1e-16f);
    __shared__ float2 red[128];
    red[t] = make_float2(accx * inv, accy * inv);
    __syncthreads();
    if (t < 32) {
        float2 r0 = red[t], r1 = red[t + 32], r2 = red[t + 64], r3 = red[t + 96];
        float2 b = *(const float2*)&bias1[t * 2];
        float vx = (r0.x + r1.x + r2.x + r3.x) * 0.25f + b.x;
        float vy = (r0.y + r1.y + r2.y + r3.y) * 0.25f + b.y;
        *(float2*)&h1[(size_t)d * C_CH + t * 2] =
            make_float2(fmaxf(vx, 0.f), fmaxf(vy, 0.f));
    }
}

// ---------------- batch-norm stats ----------------
__global__ void k_bnstats(const float* __restrict__ h1, float* __restrict__ bn, int n) {
    int t = threadIdx.x;
    int c = t & 63, rg = t >> 6;
    float s = 0.f, s2 = 0.f;
    for (int r = blockIdx.x * 4 + rg; r < n; r += gridDim.x * 4) {
        float v = h1[(size_t)r * C_CH + c];
        s += v;
        s2 += v * v;
    }
    __shared__ float ls[256], ls2[256];
    ls[t] = s; ls2[t] = s2;
    __syncthreads();
    if (t < 64) {
        s = ls[t] + ls[t + 64] + ls[t + 128] + ls[t + 192];
        s2 = ls2[t] + ls2[t + 64] + ls2[t + 128] + ls2[t + 192];
        atomicAdd(&bn[c], s);
        atomicAdd(&bn[64 + c], s2);
    }
}

// ---------------- layer 2 GEMM (MFMA fp16): x2 = BN(h1) @ W2^T, fused as2/ad2/nf ----------
__global__ __launch_bounds__(256) void k_gemm2(
    const float* __restrict__ h1, const float* __restrict__ W2,
    const float* __restrict__ att_s, const float* __restrict__ att_d,
    const float* __restrict__ bn, __half* __restrict__ x2h,
    float* __restrict__ as2, float* __restrict__ ad2, float* __restrict__ nf, int n) {
    __shared__ __align__(16) _Float16 bs[2 * 16 * 64 * 8];  // 32 KB
    __shared__ __align__(16) _Float16 as_[2 * 4 * 64 * 8];  // 8 KB
    __shared__ float nq[64][4];
    int t = threadIdx.x;
    int r0 = blockIdx.x * MBLK;
    {
        int c = t;
        const float4* wrow = (const float4*)(W2 + (size_t)c * C_CH);
        int nt = c >> 4, cl = c & 15;
#pragma unroll
        for (int ch = 0; ch < 8; ++ch) {
            float4 f0 = wrow[ch * 2], f1 = wrow[ch * 2 + 1];
            int ks = ch >> 2, lg = ch & 3;
            _Float16* dst = &bs[(((ks * 16 + nt) * 64) + (lg * 16 + cl)) * 8];
            dst[0] = (_Float16)f0.x; dst[1] = (_Float16)f0.y;
            dst[2] = (_Float16)f0.z; dst[3] = (_Float16)f0.w;
            dst[4] = (_Float16)f1.x; dst[5] = (_Float16)f1.y;
            dst[6] = (_Float16)f1.z; dst[7] = (_Float16)f1.w;
        }
    }
    {
        int row = t >> 2, q = t & 3;
        int rr = r0 + row;
        int mt = row >> 4, rl = row & 15;
        const float invN = 1.f / (float)n;
        const float4* hrow = (const float4*)(h1 + (size_t)rr * C_CH);
#pragma unroll
        for (int cc = 0; cc < 2; ++cc) {
            int ch = q * 2 + cc;
            float4 f0 = make_float4(0, 0, 0, 0), f1 = make_float4(0, 0, 0, 0);
            if (rr < n) { f0 = hrow[ch * 2]; f1 = hrow[ch * 2 + 1]; }
            float4 s0 = *(const float4*)&bn[ch * 8];
            float4 s1 = *(const float4*)&bn[ch * 8 + 4];
            float4 q0 = *(const float4*)&bn[64 + ch * 8];
            float4 q1 = *(const float4*)&bn[64 + ch * 8 + 4];
            float4 mu0 = make_float4(s0.x * invN, s0.y * invN, s0.z * invN, s0.w * invN);
            float4 mu1 = make_float4(s1.x * invN, s1.y * invN, s1.z * invN, s1.w * invN);
            float4 rs0 = make_float4(rsqrtf(q0.x * invN - mu0.x * mu0.x + 1e-5f),
                                     rsqrtf(q0.y * invN - mu0.y * mu0.y + 1e-5f),
                                     rsqrtf(q0.z * invN - mu0.z * mu0.z + 1e-5f),
                                     rsqrtf(q0.w * invN - mu0.w * mu0.w + 1e-5f));
            float4 rs1 = make_float4(rsqrtf(q1.x * invN - mu1.x * mu1.x + 1e-5f),
                                     rsqrtf(q1.y * invN - mu1.y * mu1.y + 1e-5f),
                                     rsqrtf(q1.z * invN - mu1.z * mu1.z + 1e-5f),
                                     rsqrtf(q1.w * invN - mu1.w * mu1.w + 1e-5f));
            int ks = ch >> 2, lg = ch & 3;
            _Float16* dst = &as_[(((ks * 4 + mt) * 64) + (lg * 16 + rl)) * 8];
            dst[0] = (_Float16)((f0.x - mu0.x) * rs0.x);
            dst[1] = (_Float16)((f0.y - mu0.y) * rs0.y);
            dst[2] = (_Float16)((f0.z - mu0.z) * rs0.z);
            dst[3] = (_Float16)((f0.w - mu0.w) * rs0.w);
            dst[4] = (_Float16)((f1.x - mu1.x) * rs1.x);
            dst[5] = (_Float16)((f1.y - mu1.y) * rs1.y);
            dst[6] = (_Float16)((f1.z - mu1.z) * rs1.z);
            dst[7] = (_Float16)((f1.w - mu1.w) * rs1.w);
        }
    }
    __syncthreads();
    int w = t >> 6, l = t & 63;
    f32x4 acc[4][4];
#pragma unroll
    for (int mt = 0; mt < 4; ++mt)
#pragma unroll
        for (int nt = 0; nt < 4; ++nt) acc[mt][nt] = (f32x4){0.f, 0.f, 0.f, 0.f};
#pragma unroll
    for (int ks = 0; ks < 2; ++ks) {
        half8 af[4], bf[4];
#pragma unroll
        for (int mt = 0; mt < 4; ++mt)
            af[mt] = *(const half8*)&as_[(((ks * 4 + mt) * 64) + l) * 8];
#pragma unroll
        for (int nt = 0; nt < 4; ++nt)
            bf[nt] = *(const half8*)&bs[(((ks * 16 + (w * 4 + nt)) * 64) + l) * 8];
#pragma unroll
        for (int mt = 0; mt < 4; ++mt)
#pragma unroll
            for (int nt = 0; nt < 4; ++nt)
                acc[mt][nt] = __builtin_amdgcn_mfma_f32_16x16x32_f16(af[mt], bf[nt],
                                                                     acc[mt][nt], 0, 0, 0);
    }
    int cl = l & 15, rg = l >> 4;
    float atv_s[4], atv_d[4];
#pragma unroll
    for (int nt = 0; nt < 4; ++nt) {
        atv_s[nt] = att_s[w * 64 + nt * 16 + cl];
        atv_d[nt] = att_d[w * 64 + nt * 16 + cl];
    }
#pragma unroll
    for (int mt = 0; mt < 4; ++mt) {
#pragma unroll
        for (int r = 0; r < 4; ++r) {
            int rr = r0 + mt * 16 + rg * 4 + r;
            float vs = 0.f, vd = 0.f, vq = 0.f;
#pragma unroll
            for (int nt = 0; nt < 4; ++nt) {
                float v = acc[mt][nt][r];
                vs += atv_s[nt] * v;
                vd += atv_d[nt] * v;
                vq += v * v;
                if (rr < n)
                    x2h[(size_t)rr * C_HC + w * 64 + nt * 16 + cl] = __float2half(v);
            }
#pragma unroll
            for (int off = 1; off < 16; off <<= 1) {
                vs += __shfl_xor(vs, off);
                vd += __shfl_xor(vd, off);
                vq += __shfl_xor(vq, off);
            }
            if (cl == 0 && rr < n) {
                as2[rr * C_H + w] = vs;
                ad2[rr * C_H + w] = vd;
                nq[mt * 16 + rg * 4 + r][w] = vq;
            }
        }
    }
    __syncthreads();
    if (t < MBLK) {
        int rr = r0 + t;
        if (rr < n) {
            float qq = nq[t][0] + nq[t][1] + nq[t][2] + nq[t][3];
            nf[rr] = fmaxf(sqrtf(qq), 1e-8f);
        }
    }
}

// ---------------- node trust + struct norms ----------------
__global__ void k_trust(const float* __restrict__ sf, const float* __restrict__ Wt,
                        const float* __restrict__ bt, float* __restrict__ trust,
                        float* __restrict__ ns, int n) {
    int i = blockIdx.x * blockDim.x + threadIdx.x;
    if (i >= n) return;
    const float4* r4 = (const float4*)(sf + (size_t)i * C_S);
    const float4* w4 = (const float4*)Wt;
    float d = 0.f, q = 0.f;
#pragma unroll
    for (int k = 0; k < 8; ++k) {
        float4 a = r4[k], w = w4[k];
        d += a.x * w.x + a.y * w.y + a.z * w.z + a.w * w.w;
        q += a.x * a.x + a.y * a.y + a.z * a.z + a.w * a.w;
    }
    trust[i] = 1.f / (1.f + expf(-(d + bt[0])));
    ns[i] = fmaxf(sqrtf(q), 1e-8f);
}

// ---------------- fused layer 2: gate + softmax + aggregate, no row staging ------------
// Block per dst node d, 128 threads (quad per edge for dots; thread per edge for gate
// MLP; all threads for accumulate). x2h rows read from global (L1/L2-resident, 10 MB
// table fits aggregate L2); dst row/struct held in registers per quad-thread.
__global__ __launch_bounds__(128) void k_fused2(
    const int* __restrict__ row_ptr, const int* __restrict__ adj_src,
    const float* __restrict__ sf, const __half* __restrict__ x2h,
    const float* __restrict__ ns, const float* __restrict__ nf,
    const float* __restrict__ trust, const float* __restrict__ as2,
    const float* __restrict__ ad2, const float* __restrict__ We1,
    const float* __restrict__ be1, const float* __restrict__ We2,
    const float* __restrict__ be2, const float* __restrict__ betas,
    const float* __restrict__ bias2, float* __restrict__ out) {
    __shared__ int js[ACH];
    __shared__ float pbuf[C_H][ACH];
    __shared__ float2 red[128];
    int d = blockIdx.x;
    int t = threadIdx.x, hh = t >> 5, cp = t & 31;
    int er = t >> 2, q = t & 3;     // quad mapping: 4 threads per edge
    int beg = row_ptr[d], end = row_ptr[d + 1];
    // dst row quarter q in registers (raw fp16 packed in float4), dst struct quarter
    float4 xdreg[8], sfdreg[2];
    {
        const float4* dr = (const float4*)(x2h + (size_t)d * C_HC + q * 64);
#pragma unroll
        for (int u = 0; u < 8; ++u) xdreg[u] = dr[u];
        const float4* sr = (const float4*)(sf + (size_t)d * C_S + q * 8);
        sfdreg[0] = sr[0]; sfdreg[1] = sr[1];
    }
    float4 ad2d = *(const float4*)&ad2[d * C_H];
    float nsd = ns[d], nfd = nf[d], trd = trust[d];
    float accx = 0.f, accy = 0.f, s_part = 0.f;
    for (int cbeg = beg; cbeg < end; cbeg += ACH) {
        int cn = min(end - cbeg, ACH);
        __syncthreads();  // prev chunk js/pbuf consumed
        if (q == 0 && er < cn) js[er] = adj_src[cbeg + er];
        __syncthreads();  // js ready
        // cosine dots: quad thread q handles halves [q*64, q*64+64) of the rows
        float fd = 0.f, sd = 0.f;
        int j = 0;
        if (er < cn) {
            j = js[er];
            const float4* grow = (const float4*)(x2h + (size_t)j * C_HC + q * 64);
#pragma unroll
            for (int u = 0; u < 8; ++u) {
                float4 a4 = grow[u];
                const __half2* pa = (const __half2*)&a4;
                const __half2* pb = (const __half2*)&xdreg[u];
#pragma unroll
                for (int k = 0; k < 4; ++k) {
                    float2 a = __half22float2(pa[k]), b = __half22float2(pb[k]);
                    fd += a.x * b.x + a.y * b.y;
                }
            }
            const float4* sj = (const float4*)(sf + (size_t)j * C_S + q * 8);
#pragma unroll
            for (int u = 0; u < 2; ++u) {
                float4 a = sj[u], b = sfdreg[u];
                sd += a.x * b.x + a.y * b.y + a.z * b.z + a.w * b.w;
            }
        }
        fd += __shfl_xor(fd, 1); fd += __shfl_xor(fd, 2);
        sd += __shfl_xor(sd, 1); sd += __shfl_xor(sd, 2);
        // gate tail: one thread per edge
        if (q == 0 && er < cn) {
            float ss = sd / (nsd * ns[j]);
            float fs = fd / (nfd * nf[j]);
            float agr = ss * fs;
            float con = fabsf(ss - fs);
            float gate = be2[0];
#pragma unroll
            for (int o = 0; o < 8; ++o) {
                float hdn = We1[o * 4 + 0] * ss + We1[o * 4 + 1] * fs +
                            We1[o * 4 + 2] * agr + We1[o * 4 + 3] * con + be1[o];
                gate += We2[o] * fmaxf(hdn, 0.f);
            }
            float eb = (1.f / (1.f + expf(-gate))) * fmaxf(agr, 0.f);
            float et = sqrtf(fmaxf(trd * trust[j], 0.f));
            float tb = et * fmaxf(0.5f * (ss + fs), 0.f);
            float g = betas[0] * ss + betas[1] * fs + betas[2] * agr +
                      betas[3] * eb + betas[4] * tb;
            float4 asj = *(const float4*)&as2[j * C_H];
            pbuf[0][er] = expf(lrelu(asj.x + ad2d.x) + g);
            pbuf[1][er] = expf(lrelu(asj.y + ad2d.y) + g);
            pbuf[2][er] = expf(lrelu(asj.z + ad2d.z) + g);
            pbuf[3][er] = expf(lrelu(asj.w + ad2d.w) + g);
        }
        __syncthreads();  // pbuf ready
        // accumulate: rows re-read from global (L1-hot from dot phase)
        for (int i = 0; i < cn; ++i) {
            int jj = js[i];
            float pv = pbuf[hh][i];
            float2 v = __half22float2(
                *(const __half2*)(x2h + (size_t)jj * C_HC + hh * 64 + cp * 2));
            accx += pv * v.x;
            accy += pv * v.y;
        }
        if (cp < cn) s_part += pbuf[hh][cp];
    }
    float s = sub_sum32(s_part);
    float inv = 1.f / (s + 1e-16f);
    red[t] = make_float2(accx * inv, accy * inv);
    __syncthreads();
    if (t < 32) {
        float2 r0 = red[t], r1 = red[t + 32], r2 = red[t + 64], r3 = red[t + 96];
        float2 b = *(const float2*)&bias2[t * 2];
        float vx = (r0.x + r1.x + r2.x + r3.x) * 0.25f + b.x;
        float vy = (r0.y + r1.y + r2.y + r3.y) * 0.25f + b.y;
        *(float2*)&out[(size_t)d * C_CH + t * 2] = make_float2(vx, vy);
    }
}

static inline size_t al256(size_t x) { return (x + 255) & ~(size_t)255; }

extern "C" void kernel_launch(void* const* d_in, const int* in_sizes, int n_in,
                              void* d_out, int out_size, void* d_ws, size_t ws_size,
                              hipStream_t stream) {
    const float* x      = (const float*)d_in[0];
    const int*   ei     = (const int*)d_in[1];
    const float* sf     = (const float*)d_in[2];
    const float* W1     = (const float*)d_in[3];
    const float* atts1  = (const float*)d_in[4];
    const float* attd1  = (const float*)d_in[5];
    const float* bias1  = (const float*)d_in[6];
    const float* W2     = (const float*)d_in[7];
    const float* atts2  = (const float*)d_in[8];
    const float* attd2  = (const float*)d_in[9];
    const float* bias2  = (const float*)d_in[10];
    const float* Wt     = (const float*)d_in[11];
    const float* bt     = (const float*)d_in[12];
    const float* We1    = (const float*)d_in[13];
    const float* be1    = (const float*)d_in[14];
    const float* We2    = (const float*)d_in[15];
    const float* be2    = (const float*)d_in[16];
    const float* betas  = (const float*)d_in[17];

    const int N = in_sizes[0] / C_DIN;
    const int E = in_sizes[1] / 2;
    const int* srcs = ei;
    const int* dsts = ei + E;

    // workspace carve-up; disjoint-lifetime aliases: x2h reuses hhlf,
    // as2/ad2 reuse a_s1/a_d1
    char* p = (char*)d_ws;
    size_t off = 0;
    auto take = [&](size_t bytes) { char* r = p + off; off = al256(off + bytes); return r; };
    __half* hhlf  = (__half*)take((size_t)N * C_HC * 2);  // layer-1 h (fp16); reused as x2h
    float* h1     = (float*)take((size_t)N * C_CH * 4);
    float* a_s1   = (float*)take((size_t)N * C_H * 4);    // reused as as2
    float* a_d1   = (float*)take((size_t)N * C_H * 4);    // reused as ad2
    float* nf     = (float*)take((size_t)N * 4);
    float* ns     = (float*)take((size_t)N * 4);
    float* trust  = (float*)take((size_t)N * 4);
    int*   deg    = (int*)take((size_t)N * 4);
    int*   rowp   = (int*)take((size_t)(N + 1) * 4);
    int*   cursor = (int*)take((size_t)N * 4);
    int*   adj_s  = (int*)take((size_t)E * 4);
    float* bn     = (float*)take(128 * 4);  // [0:64) sum, [64:128) sumsq
    (void)ws_size;
    __half* x2h = hhlf;   // alias: hhlf dead after k_layer1, x2h born in k_gemm2
    float* as2  = a_s1;   // alias: a_s1 dead after k_layer1
    float* ad2  = a_d1;   // alias: a_d1 dead after k_layer1

    hipMemsetAsync(deg, 0, (size_t)N * 4, stream);
    hipMemsetAsync(bn, 0, 128 * 4, stream);

    // CSR build
    k_count<<<(E + 255) / 256, 256, 0, stream>>>(dsts, deg, E);
    k_scan<<<1, 1024, 0, stream>>>(deg, rowp, cursor, N);
    k_scatter<<<(E + 255) / 256, 256, 0, stream>>>(srcs, dsts, cursor, adj_s, E);

    // layer 1
    k_gemm1<<<(N + MBLK - 1) / MBLK, 256, 0, stream>>>(x, W1, atts1, attd1, hhlf, a_s1, a_d1, N);
    k_layer1<<<N, 128, 0, stream>>>(rowp, adj_s, hhlf, a_s1, a_d1, bias1, h1);
    k_bnstats<<<128, 256, 0, stream>>>(h1, bn, N);

    // layer 2
    k_gemm2<<<(N + MBLK - 1) / MBLK, 256, 0, stream>>>(h1, W2, atts2, attd2, bn, x2h,
                                                       as2, ad2, nf, N);
    k_trust<<<(N + 255) / 256, 256, 0, stream>>>(sf, Wt, bt, trust, ns, N);
    k_fused2<<<N, 128, 0, stream>>>(rowp, adj_s, sf, x2h, ns, nf, trust, as2, ad2,
                                    We1, be1, We2, be2, betas, bias2, (float*)d_out);
}

// Round 13
// 307.436 us; speedup vs baseline: 1.1075x; 1.1075x over previous
//
#include <hip/hip_runtime.h>
#include <hip/hip_bf16.h>
#include <hip/hip_fp16.h>

// Problem constants (verified against setup_inputs)
#define C_DIN 128
#define C_H 4
#define C_CH 64     // per-head channels (CHID == COUT == 64)
#define C_HC 256    // H * CH
#define C_S 32
#define ACH 32      // aggregation / fusion chunk (edges)
#define MBLK 64     // GEMM M-tile (rows per block)
#define XROW 264    // LDS row stride in halves (132 dwords; 33 float4) -> 2-way-free acc reads

typedef __attribute__((ext_vector_type(8))) _Float16 half8;
typedef __attribute__((ext_vector_type(4))) float f32x4;

__device__ __forceinline__ float lrelu(float x) { return x >= 0.f ? x : 0.2f * x; }

// reduction within an aligned 32-lane subgroup
__device__ __forceinline__ float sub_sum32(float v) {
#pragma unroll
    for (int off = 16; off > 0; off >>= 1) v += __shfl_xor(v, off);
    return v;
}

// ---------------- CSR build ----------------
__global__ void k_count(const int* __restrict__ dst, int* __restrict__ deg, int E) {
    int e = blockIdx.x * blockDim.x + threadIdx.x;
    if (e < E) atomicAdd(&deg[dst[e]], 1);
}

__global__ void k_scan(const int* __restrict__ deg, int* __restrict__ row_ptr,
                       int* __restrict__ cursor, int n) {
    __shared__ int part[1024];
    int t = threadIdx.x;
    const int C = (n + 1023) / 1024;
    int base = t * C;
    int s = 0;
    for (int k = 0; k < C; ++k) {
        int idx = base + k;
        if (idx < n) s += deg[idx];
    }
    part[t] = s;
    __syncthreads();
    for (int off = 1; off < 1024; off <<= 1) {
        int v = (t >= off) ? part[t - off] : 0;
        __syncthreads();
        part[t] += v;
        __syncthreads();
    }
    int run = (t == 0) ? 0 : part[t - 1];
    for (int k = 0; k < C; ++k) {
        int idx = base + k;
        if (idx < n) { row_ptr[idx] = run; cursor[idx] = run; run += deg[idx]; }
    }
    if (t == 1023) row_ptr[n] = run;
}

__global__ void k_scatter(const int* __restrict__ src, const int* __restrict__ dst,
                          int* __restrict__ cursor, int* __restrict__ adj_src, int E) {
    int e = blockIdx.x * blockDim.x + threadIdx.x;
    if (e < E) {
        int d = dst[e];
        int p = atomicAdd(&cursor[d], 1);
        adj_src[p] = src[e];
    }
}

// ---------------- W1/W2 -> MFMA B-fragment-layout fp16 (once) ----------------
// B-frag index i = (ks*16 + nt)*64 + lpos; maps to W[c][k]: c = nt*16 + (lpos&15),
// k = (ks*4 + (lpos>>4))*8 + e.  W1: ks<4 (4096 frags), W2: ks<2 (2048 frags).
__global__ void k_prepw(const float* __restrict__ W1, const float* __restrict__ W2,
                        _Float16* __restrict__ W1f, _Float16* __restrict__ W2f) {
    int i = blockIdx.x * blockDim.x + threadIdx.x;
    if (i < 4096) {
        int ks = i >> 10, rem = i & 1023, nt = rem >> 6, lpos = rem & 63;
        int c = nt * 16 + (lpos & 15);
        int kb = (ks * 4 + (lpos >> 4)) * 8;
        const float4* src = (const float4*)(W1 + (size_t)c * C_DIN + kb);
        float4 f0 = src[0], f1 = src[1];
        _Float16* dst = &W1f[(size_t)i * 8];
        dst[0] = (_Float16)f0.x; dst[1] = (_Float16)f0.y;
        dst[2] = (_Float16)f0.z; dst[3] = (_Float16)f0.w;
        dst[4] = (_Float16)f1.x; dst[5] = (_Float16)f1.y;
        dst[6] = (_Float16)f1.z; dst[7] = (_Float16)f1.w;
    } else if (i < 4096 + 2048) {
        int ii = i - 4096;
        int ks = ii >> 10, rem = ii & 1023, nt = rem >> 6, lpos = rem & 63;
        int c = nt * 16 + (lpos & 15);
        int kb = (ks * 4 + (lpos >> 4)) * 8;
        const float4* src = (const float4*)(W2 + (size_t)c * C_CH + kb);
        float4 f0 = src[0], f1 = src[1];
        _Float16* dst = &W2f[(size_t)ii * 8];
        dst[0] = (_Float16)f0.x; dst[1] = (_Float16)f0.y;
        dst[2] = (_Float16)f0.z; dst[3] = (_Float16)f0.w;
        dst[4] = (_Float16)f1.x; dst[5] = (_Float16)f1.y;
        dst[6] = (_Float16)f1.z; dst[7] = (_Float16)f1.w;
    }
}

// ---------------- layer 1 GEMM (MFMA fp16): h = x @ W1^T, fused a_s1/a_d1 ----------------
// B-frags read from pre-laid-out global W1f (L2-resident); LDS only for A tile (16 KB).
__global__ __launch_bounds__(256) void k_gemm1(
    const float* __restrict__ x, const _Float16* __restrict__ W1f,
    const float* __restrict__ att_s, const float* __restrict__ att_d,
    __half* __restrict__ hh_out, float* __restrict__ a_s, float* __restrict__ a_d, int n) {
    __shared__ __align__(16) _Float16 as_[4 * 4 * 64 * 8];  // 16 KB
    int t = threadIdx.x;
    int r0 = blockIdx.x * MBLK;
    {
        int row = t >> 2, q = t & 3;
        int rr = r0 + row;
        int mt = row >> 4, rl = row & 15;
        const float4* xrow = (const float4*)(x + (size_t)rr * C_DIN);
#pragma unroll
        for (int cc = 0; cc < 4; ++cc) {
            int ch = q * 4 + cc;
            float4 f0 = make_float4(0, 0, 0, 0), f1 = make_float4(0, 0, 0, 0);
            if (rr < n) { f0 = xrow[ch * 2]; f1 = xrow[ch * 2 + 1]; }
            int ks = ch >> 2, lg = ch & 3;
            _Float16* dst = &as_[(((ks * 4 + mt) * 64) + (lg * 16 + rl)) * 8];
            dst[0] = (_Float16)f0.x; dst[1] = (_Float16)f0.y;
            dst[2] = (_Float16)f0.z; dst[3] = (_Float16)f0.w;
            dst[4] = (_Float16)f1.x; dst[5] = (_Float16)f1.y;
            dst[6] = (_Float16)f1.z; dst[7] = (_Float16)f1.w;
        }
    }
    __syncthreads();
    int w = t >> 6, l = t & 63;
    const half8* Wv = (const half8*)W1f;
    f32x4 acc[4][4];
#pragma unroll
    for (int mt = 0; mt < 4; ++mt)
#pragma unroll
        for (int nt = 0; nt < 4; ++nt) acc[mt][nt] = (f32x4){0.f, 0.f, 0.f, 0.f};
#pragma unroll
    for (int ks = 0; ks < 4; ++ks) {
        half8 af[4], bf[4];
#pragma unroll
        for (int mt = 0; mt < 4; ++mt)
            af[mt] = *(const half8*)&as_[(((ks * 4 + mt) * 64) + l) * 8];
#pragma unroll
        for (int nt = 0; nt < 4; ++nt)
            bf[nt] = Wv[((ks * 16 + (w * 4 + nt)) * 64) + l];
#pragma unroll
        for (int mt = 0; mt < 4; ++mt)
#pragma unroll
            for (int nt = 0; nt < 4; ++nt)
                acc[mt][nt] = __builtin_amdgcn_mfma_f32_16x16x32_f16(af[mt], bf[nt],
                                                                     acc[mt][nt], 0, 0, 0);
    }
    int cl = l & 15, rg = l >> 4;
    float atv_s[4], atv_d[4];
#pragma unroll
    for (int nt = 0; nt < 4; ++nt) {
        atv_s[nt] = att_s[w * 64 + nt * 16 + cl];
        atv_d[nt] = att_d[w * 64 + nt * 16 + cl];
    }
#pragma unroll
    for (int mt = 0; mt < 4; ++mt) {
#pragma unroll
        for (int r = 0; r < 4; ++r) {
            int rr = r0 + mt * 16 + rg * 4 + r;
            float vs = 0.f, vd = 0.f;
#pragma unroll
            for (int nt = 0; nt < 4; ++nt) {
                float v = acc[mt][nt][r];
                vs += atv_s[nt] * v;
                vd += atv_d[nt] * v;
                if (rr < n)
                    hh_out[(size_t)rr * C_HC + w * 64 + nt * 16 + cl] = __float2half(v);
            }
#pragma unroll
            for (int off = 1; off < 16; off <<= 1) {
                vs += __shfl_xor(vs, off);
                vd += __shfl_xor(vd, off);
            }
            if (cl == 0 && rr < n) { a_s[rr * C_H + w] = vs; a_d[rr * C_H + w] = vd; }
        }
    }
}

// ---------------- layer 1 aggregation: single pass, unnormalized exp ----------------
__global__ void k_layer1(const int* __restrict__ row_ptr, const int* __restrict__ adj_src,
                         const __half* __restrict__ hhlf, const float* __restrict__ a_s,
                         const float* __restrict__ a_d, const float* __restrict__ bias1,
                         float* __restrict__ h1) {
    int d = blockIdx.x;
    int t = threadIdx.x, hh = t >> 5, cp = t & 31;
    int beg = row_ptr[d], end = row_ptr[d + 1];
    float adh = a_d[d * C_H + hh];
    float p_self = expf(lrelu(a_s[d * C_H + hh] + adh));
    __shared__ float alpha_l[C_H][ACH];
    __shared__ int src_l[ACH];
    const __half2* selfrow = (const __half2*)(hhlf + (size_t)d * C_HC + hh * 64);
    float2 sv = __half22float2(selfrow[cp]);
    float accx = p_self * sv.x, accy = p_self * sv.y;
    float s_part = (cp == 0) ? p_self : 0.f;
    for (int cbeg = beg; cbeg < end; cbeg += ACH) {
        int cn = min(end - cbeg, ACH);
        __syncthreads();
        if (cp < cn) {
            int s = adj_src[cbeg + cp];
            if (hh == 0) src_l[cp] = s;
            float p = expf(lrelu(a_s[s * C_H + hh] + adh));
            alpha_l[hh][cp] = p;
            s_part += p;
        }
        __syncthreads();
        for (int i = 0; i < cn; ++i) {
            int s = src_l[i];
            float a = alpha_l[hh][i];
            float2 v = __half22float2(
                *(const __half2*)(hhlf + (size_t)s * C_HC + hh * 64 + cp * 2));
            accx += a * v.x;
            accy += a * v.y;
        }
    }
    float s = sub_sum32(s_part);
    float inv = 1.f / (s + 1e-16f);
    __shared__ float2 red[128];
    red[t] = make_float2(accx * inv, accy * inv);
    __syncthreads();
    if (t < 32) {
        float2 r0 = red[t], r1 = red[t + 32], r2 = red[t + 64], r3 = red[t + 96];
        float2 b = *(const float2*)&bias1[t * 2];
        float vx = (r0.x + r1.x + r2.x + r3.x) * 0.25f + b.x;
        float vy = (r0.y + r1.y + r2.y + r3.y) * 0.25f + b.y;
        *(float2*)&h1[(size_t)d * C_CH + t * 2] =
            make_float2(fmaxf(vx, 0.f), fmaxf(vy, 0.f));
    }
}

// ---------------- batch-norm stats ----------------
__global__ void k_bnstats(const float* __restrict__ h1, float* __restrict__ bn, int n) {
    int t = threadIdx.x;
    int c = t & 63, rg = t >> 6;
    float s = 0.f, s2 = 0.f;
    for (int r = blockIdx.x * 4 + rg; r < n; r += gridDim.x * 4) {
        float v = h1[(size_t)r * C_CH + c];
        s += v;
        s2 += v * v;
    }
    __shared__ float ls[256], ls2[256];
    ls[t] = s; ls2[t] = s2;
    __syncthreads();
    if (t < 64) {
        s = ls[t] + ls[t + 64] + ls[t + 128] + ls[t + 192];
        s2 = ls2[t] + ls2[t + 64] + ls2[t + 128] + ls2[t + 192];
        atomicAdd(&bn[c], s);
        atomicAdd(&bn[64 + c], s2);
    }
}

// ---------------- layer 2 GEMM (MFMA fp16): x2 = BN(h1) @ W2^T, fused as2/ad2/nf ----------
__global__ __launch_bounds__(256) void k_gemm2(
    const float* __restrict__ h1, const _Float16* __restrict__ W2f,
    const float* __restrict__ att_s, const float* __restrict__ att_d,
    const float* __restrict__ bn, __half* __restrict__ x2h,
    float* __restrict__ as2, float* __restrict__ ad2, float* __restrict__ nf, int n) {
    __shared__ __align__(16) _Float16 as_[2 * 4 * 64 * 8];  // 8 KB
    __shared__ float nq[64][4];
    int t = threadIdx.x;
    int r0 = blockIdx.x * MBLK;
    {
        int row = t >> 2, q = t & 3;
        int rr = r0 + row;
        int mt = row >> 4, rl = row & 15;
        const float invN = 1.f / (float)n;
        const float4* hrow = (const float4*)(h1 + (size_t)rr * C_CH);
#pragma unroll
        for (int cc = 0; cc < 2; ++cc) {
            int ch = q * 2 + cc;
            float4 f0 = make_float4(0, 0, 0, 0), f1 = make_float4(0, 0, 0, 0);
            if (rr < n) { f0 = hrow[ch * 2]; f1 = hrow[ch * 2 + 1]; }
            float4 s0 = *(const float4*)&bn[ch * 8];
            float4 s1 = *(const float4*)&bn[ch * 8 + 4];
            float4 q0 = *(const float4*)&bn[64 + ch * 8];
            float4 q1 = *(const float4*)&bn[64 + ch * 8 + 4];
            float4 mu0 = make_float4(s0.x * invN, s0.y * invN, s0.z * invN, s0.w * invN);
            float4 mu1 = make_float4(s1.x * invN, s1.y * invN, s1.z * invN, s1.w * invN);
            float4 rs0 = make_float4(rsqrtf(q0.x * invN - mu0.x * mu0.x + 1e-5f),
                                     rsqrtf(q0.y * invN - mu0.y * mu0.y + 1e-5f),
                                     rsqrtf(q0.z * invN - mu0.z * mu0.z + 1e-5f),
                                     rsqrtf(q0.w * invN - mu0.w * mu0.w + 1e-5f));
            float4 rs1 = make_float4(rsqrtf(q1.x * invN - mu1.x * mu1.x + 1e-5f),
                                     rsqrtf(q1.y * invN - mu1.y * mu1.y + 1e-5f),
                                     rsqrtf(q1.z * invN - mu1.z * mu1.z + 1e-5f),
                                     rsqrtf(q1.w * invN - mu1.w * mu1.w + 1e-5f));
            int ks = ch >> 2, lg = ch & 3;
            _Float16* dst = &as_[(((ks * 4 + mt) * 64) + (lg * 16 + rl)) * 8];
            dst[0] = (_Float16)((f0.x - mu0.x) * rs0.x);
            dst[1] = (_Float16)((f0.y - mu0.y) * rs0.y);
            dst[2] = (_Float16)((f0.z - mu0.z) * rs0.z);
            dst[3] = (_Float16)((f0.w - mu0.w) * rs0.w);
            dst[4] = (_Float16)((f1.x - mu1.x) * rs1.x);
            dst[5] = (_Float16)((f1.y - mu1.y) * rs1.y);
            dst[6] = (_Float16)((f1.z - mu1.z) * rs1.z);
            dst[7] = (_Float16)((f1.w - mu1.w) * rs1.w);
        }
    }
    __syncthreads();
    int w = t >> 6, l = t & 63;
    const half8* Wv = (const half8*)W2f;
    f32x4 acc[4][4];
#pragma unroll
    for (int mt = 0; mt < 4; ++mt)
#pragma unroll
        for (int nt = 0; nt < 4; ++nt) acc[mt][nt] = (f32x4){0.f, 0.f, 0.f, 0.f};
#pragma unroll
    for (int ks = 0; ks < 2; ++ks) {
        half8 af[4], bf[4];
#pragma unroll
        for (int mt = 0; mt < 4; ++mt)
            af[mt] = *(const half8*)&as_[(((ks * 4 + mt) * 64) + l) * 8];
#pragma unroll
        for (int nt = 0; nt < 4; ++nt)
            bf[nt] = Wv[((ks * 16 + (w * 4 + nt)) * 64) + l];
#pragma unroll
        for (int mt = 0; mt < 4; ++mt)
#pragma unroll
            for (int nt = 0; nt < 4; ++nt)
                acc[mt][nt] = __builtin_amdgcn_mfma_f32_16x16x32_f16(af[mt], bf[nt],
                                                                     acc[mt][nt], 0, 0, 0);
    }
    int cl = l & 15, rg = l >> 4;
    float atv_s[4], atv_d[4];
#pragma unroll
    for (int nt = 0; nt < 4; ++nt) {
        atv_s[nt] = att_s[w * 64 + nt * 16 + cl];
        atv_d[nt] = att_d[w * 64 + nt * 16 + cl];
    }
#pragma unroll
    for (int mt = 0; mt < 4; ++mt) {
#pragma unroll
        for (int r = 0; r < 4; ++r) {
            int rr = r0 + mt * 16 + rg * 4 + r;
            float vs = 0.f, vd = 0.f, vq = 0.f;
#pragma unroll
            for (int nt = 0; nt < 4; ++nt) {
                float v = acc[mt][nt][r];
                vs += atv_s[nt] * v;
                vd += atv_d[nt] * v;
                vq += v * v;
                if (rr < n)
                    x2h[(size_t)rr * C_HC + w * 64 + nt * 16 + cl] = __float2half(v);
            }
#pragma unroll
            for (int off = 1; off < 16; off <<= 1) {
                vs += __shfl_xor(vs, off);
                vd += __shfl_xor(vd, off);
                vq += __shfl_xor(vq, off);
            }
            if (cl == 0 && rr < n) {
                as2[rr * C_H + w] = vs;
                ad2[rr * C_H + w] = vd;
                nq[mt * 16 + rg * 4 + r][w] = vq;
            }
        }
    }
    __syncthreads();
    if (t < MBLK) {
        int rr = r0 + t;
        if (rr < n) {
            float qq = nq[t][0] + nq[t][1] + nq[t][2] + nq[t][3];
            nf[rr] = fmaxf(sqrtf(qq), 1e-8f);
        }
    }
}

// ---------------- node trust + struct norms ----------------
__global__ void k_trust(const float* __restrict__ sf, const float* __restrict__ Wt,
                        const float* __restrict__ bt, float* __restrict__ trust,
                        float* __restrict__ ns, int n) {
    int i = blockIdx.x * blockDim.x + threadIdx.x;
    if (i >= n) return;
    const float4* r4 = (const float4*)(sf + (size_t)i * C_S);
    const float4* w4 = (const float4*)Wt;
    float d = 0.f, q = 0.f;
#pragma unroll
    for (int k = 0; k < 8; ++k) {
        float4 a = r4[k], w = w4[k];
        d += a.x * w.x + a.y * w.y + a.z * w.z + a.w * w.w;
        q += a.x * a.x + a.y * a.y + a.z * a.z + a.w * a.w;
    }
    trust[i] = 1.f / (1.f + expf(-(d + bt[0])));
    ns[i] = fmaxf(sqrtf(q), 1e-8f);
}

// ---------------- fused layer 2: stage+dot fused, LDS accumulate ----------------
// Block per dst node d, 128 threads. Per 32-edge chunk: each aligned 32-lane group
// stages one row (lane = one float4, linear LDS write = conflict-free) AND computes
// the feature/struct dots from those same registers via 32-lane shuffle reduce.
// Gate MLP: one thread per edge. Accumulate: 2-way-free LDS reads.
__global__ __launch_bounds__(128) void k_fused2(
    const int* __restrict__ row_ptr, const int* __restrict__ adj_src,
    const float* __restrict__ sf, const __half* __restrict__ x2h,
    const float* __restrict__ ns, const float* __restrict__ nf,
    const float* __restrict__ trust, const float* __restrict__ as2,
    const float* __restrict__ ad2, const float* __restrict__ We1,
    const float* __restrict__ be1, const float* __restrict__ We2,
    const float* __restrict__ be2, const float* __restrict__ betas,
    const float* __restrict__ bias2, float* __restrict__ out) {
    __shared__ __align__(16) _Float16 xr[ACH * XROW];  // 16.5 KB staged src rows
    __shared__ int js[ACH];
    __shared__ float fdL[ACH], sdL[ACH];
    __shared__ float pbuf[C_H][ACH];
    __shared__ float2 red[128];
    int d = blockIdx.x;
    int t = threadIdx.x, hh = t >> 5, cp = t & 31;
    int beg = row_ptr[d], end = row_ptr[d + 1];
    // per-lane dst fragments: lane (t&31) holds dst-row quarter (float4 of packed fp16)
    // and one struct element
    float4 xd4 = ((const float4*)(x2h + (size_t)d * C_HC))[cp];
    float sfdl = sf[(size_t)d * C_S + cp];
    float4 ad2d = *(const float4*)&ad2[d * C_H];
    float nsd = ns[d], nfd = nf[d], trd = trust[d];
    float accx = 0.f, accy = 0.f, s_part = 0.f;
    for (int cbeg = beg; cbeg < end; cbeg += ACH) {
        int cn = min(end - cbeg, ACH);
        __syncthreads();  // previous chunk fully consumed
        if (t < cn) js[t] = adj_src[cbeg + t];
        __syncthreads();  // js ready
        // stage + dot: 32-lane group (t>>5) handles rows r = group, group+4, ...
        for (int r = hh; r < cn; r += 4) {
            int j = js[r];
            float4 v4 = ((const float4*)(x2h + (size_t)j * C_HC))[cp];
            ((float4*)&xr[(size_t)r * XROW])[cp] = v4;
            float fdp = 0.f;
            const __half2* pa = (const __half2*)&v4;
            const __half2* pb = (const __half2*)&xd4;
#pragma unroll
            for (int k = 0; k < 4; ++k) {
                float2 a = __half22float2(pa[k]), b = __half22float2(pb[k]);
                fdp += a.x * b.x + a.y * b.y;
            }
            float sdp = sf[(size_t)j * C_S + cp] * sfdl;
#pragma unroll
            for (int off = 16; off > 0; off >>= 1) {
                fdp += __shfl_xor(fdp, off);
                sdp += __shfl_xor(sdp, off);
            }
            if (cp == 0) { fdL[r] = fdp; sdL[r] = sdp; }
        }
        __syncthreads();  // rows + dots ready
        // gate MLP: one thread per edge
        if (t < cn) {
            int j = js[t];
            float ss = sdL[t] / (nsd * ns[j]);
            float fs = fdL[t] / (nfd * nf[j]);
            float agr = ss * fs;
            float con = fabsf(ss - fs);
            float gate = be2[0];
#pragma unroll
            for (int o = 0; o < 8; ++o) {
                float hdn = We1[o * 4 + 0] * ss + We1[o * 4 + 1] * fs +
                            We1[o * 4 + 2] * agr + We1[o * 4 + 3] * con + be1[o];
                gate += We2[o] * fmaxf(hdn, 0.f);
            }
            float eb = (1.f / (1.f + expf(-gate))) * fmaxf(agr, 0.f);
            float et = sqrtf(fmaxf(trd * trust[j], 0.f));
            float tb = et * fmaxf(0.5f * (ss + fs), 0.f);
            float g = betas[0] * ss + betas[1] * fs + betas[2] * agr +
                      betas[3] * eb + betas[4] * tb;
            float4 asj = *(const float4*)&as2[j * C_H];
            pbuf[0][t] = expf(lrelu(asj.x + ad2d.x) + g);
            pbuf[1][t] = expf(lrelu(asj.y + ad2d.y) + g);
            pbuf[2][t] = expf(lrelu(asj.z + ad2d.z) + g);
            pbuf[3][t] = expf(lrelu(asj.w + ad2d.w) + g);
        }
        __syncthreads();  // pbuf ready
        // accumulate from staged rows (dword i*132 + hh*32 + cp -> 2-way free)
        for (int i = 0; i < cn; ++i) {
            float pv = pbuf[hh][i];
            float2 v = __half22float2(
                *(const __half2*)&xr[(size_t)i * XROW + hh * 64 + cp * 2]);
            accx += pv * v.x;
            accy += pv * v.y;
        }
        if (cp < cn) s_part += pbuf[hh][cp];
    }
    float s = sub_sum32(s_part);
    float inv = 1.f / (s + 1e-16f);
    red[t] = make_float2(accx * inv, accy * inv);
    __syncthreads();
    if (t < 32) {
        float2 r0 = red[t], r1 = red[t + 32], r2 = red[t + 64], r3 = red[t + 96];
        float2 b = *(const float2*)&bias2[t * 2];
        float vx = (r0.x + r1.x + r2.x + r3.x) * 0.25f + b.x;
        float vy = (r0.y + r1.y + r2.y + r3.y) * 0.25f + b.y;
        *(float2*)&out[(size_t)d * C_CH + t * 2] = make_float2(vx, vy);
    }
}

static inline size_t al256(size_t x) { return (x + 255) & ~(size_t)255; }

extern "C" void kernel_launch(void* const* d_in, const int* in_sizes, int n_in,
                              void* d_out, int out_size, void* d_ws, size_t ws_size,
                              hipStream_t stream) {
    const float* x      = (const float*)d_in[0];
    const int*   ei     = (const int*)d_in[1];
    const float* sf     = (const float*)d_in[2];
    const float* W1     = (const float*)d_in[3];
    const float* atts1  = (const float*)d_in[4];
    const float* attd1  = (const float*)d_in[5];
    const float* bias1  = (const float*)d_in[6];
    const float* W2     = (const float*)d_in[7];
    const float* atts2  = (const float*)d_in[8];
    const float* attd2  = (const float*)d_in[9];
    const float* bias2  = (const float*)d_in[10];
    const float* Wt     = (const float*)d_in[11];
    const float* bt     = (const float*)d_in[12];
    const float* We1    = (const float*)d_in[13];
    const float* be1    = (const float*)d_in[14];
    const float* We2    = (const float*)d_in[15];
    const float* be2    = (const float*)d_in[16];
    const float* betas  = (const float*)d_in[17];

    const int N = in_sizes[0] / C_DIN;
    const int E = in_sizes[1] / 2;
    const int* srcs = ei;
    const int* dsts = ei + E;

    // workspace carve-up; disjoint-lifetime aliases: x2h reuses hhlf,
    // as2/ad2 reuse a_s1/a_d1
    char* p = (char*)d_ws;
    size_t off = 0;
    auto take = [&](size_t bytes) { char* r = p + off; off = al256(off + bytes); return r; };
    __half* hhlf  = (__half*)take((size_t)N * C_HC * 2);  // layer-1 h (fp16); reused as x2h
    float* h1     = (float*)take((size_t)N * C_CH * 4);
    float* a_s1   = (float*)take((size_t)N * C_H * 4);    // reused as as2
    float* a_d1   = (float*)take((size_t)N * C_H * 4);    // reused as ad2
    float* nf     = (float*)take((size_t)N * 4);
    float* ns     = (float*)take((size_t)N * 4);
    float* trust  = (float*)take((size_t)N * 4);
    int*   deg    = (int*)take((size_t)N * 4);
    int*   rowp   = (int*)take((size_t)(N + 1) * 4);
    int*   cursor = (int*)take((size_t)N * 4);
    int*   adj_s  = (int*)take((size_t)E * 4);
    _Float16* W1f = (_Float16*)take(4096 * 8 * 2);        // W1 in B-frag layout
    _Float16* W2f = (_Float16*)take(2048 * 8 * 2);        // W2 in B-frag layout
    float* bn     = (float*)take(128 * 4);  // [0:64) sum, [64:128) sumsq
    (void)ws_size;
    __half* x2h = hhlf;   // alias: hhlf dead after k_layer1, x2h born in k_gemm2
    float* as2  = a_s1;   // alias: a_s1 dead after k_layer1
    float* ad2  = a_d1;   // alias: a_d1 dead after k_layer1

    hipMemsetAsync(deg, 0, (size_t)N * 4, stream);
    hipMemsetAsync(bn, 0, 128 * 4, stream);

    // weight fragment prep + CSR build
    k_prepw<<<24, 256, 0, stream>>>(W1, W2, W1f, W2f);
    k_count<<<(E + 255) / 256, 256, 0, stream>>>(dsts, deg, E);
    k_scan<<<1, 1024, 0, stream>>>(deg, rowp, cursor, N);
    k_scatter<<<(E + 255) / 256, 256, 0, stream>>>(srcs, dsts, cursor, adj_s, E);

    // layer 1
    k_gemm1<<<(N + MBLK - 1) / MBLK, 256, 0, stream>>>(x, W1f, atts1, attd1, hhlf, a_s1,
                                                       a_d1, N);
    k_layer1<<<N, 128, 0, stream>>>(rowp, adj_s, hhlf, a_s1, a_d1, bias1, h1);
    k_bnstats<<<128, 256, 0, stream>>>(h1, bn, N);

    // layer 2
    k_gemm2<<<(N + MBLK - 1) / MBLK, 256, 0, stream>>>(h1, W2f, atts2, attd2, bn, x2h,
                                                       as2, ad2, nf, N);
    k_trust<<<(N + 255) / 256, 256, 0, stream>>>(sf, Wt, bt, trust, ns, N);
    k_fused2<<<N, 128, 0, stream>>>(rowp, adj_s, sf, x2h, ns, nf, trust, as2, ad2,
                                    We1, be1, We2, be2, betas, bias2, (float*)d_out);
}

// Round 14
// 306.822 us; speedup vs baseline: 1.1097x; 1.0020x over previous
//
#include <hip/hip_runtime.h>
#include <hip/hip_bf16.h>
#include <hip/hip_fp16.h>

// Problem constants (verified against setup_inputs)
#define C_DIN 128
#define C_H 4
#define C_CH 64     // per-head channels (CHID == COUT == 64)
#define C_HC 256    // H * CH
#define C_S 32
#define MBLK 64     // GEMM M-tile (rows per block)

typedef __attribute__((ext_vector_type(8))) _Float16 half8;
typedef __attribute__((ext_vector_type(4))) float f32x4;

__device__ __forceinline__ float lrelu(float x) { return x >= 0.f ? x : 0.2f * x; }

// ---------------- CSR build ----------------
__global__ void k_count(const int* __restrict__ dst, int* __restrict__ deg, int E) {
    int e = blockIdx.x * blockDim.x + threadIdx.x;
    if (e < E) atomicAdd(&deg[dst[e]], 1);
}

__global__ void k_scan(const int* __restrict__ deg, int* __restrict__ row_ptr,
                       int* __restrict__ cursor, int n) {
    __shared__ int part[1024];
    int t = threadIdx.x;
    const int C = (n + 1023) / 1024;
    int base = t * C;
    int s = 0;
    for (int k = 0; k < C; ++k) {
        int idx = base + k;
        if (idx < n) s += deg[idx];
    }
    part[t] = s;
    __syncthreads();
    for (int off = 1; off < 1024; off <<= 1) {
        int v = (t >= off) ? part[t - off] : 0;
        __syncthreads();
        part[t] += v;
        __syncthreads();
    }
    int run = (t == 0) ? 0 : part[t - 1];
    for (int k = 0; k < C; ++k) {
        int idx = base + k;
        if (idx < n) { row_ptr[idx] = run; cursor[idx] = run; run += deg[idx]; }
    }
    if (t == 1023) row_ptr[n] = run;
}

__global__ void k_scatter(const int* __restrict__ src, const int* __restrict__ dst,
                          int* __restrict__ cursor, int* __restrict__ adj_src, int E) {
    int e = blockIdx.x * blockDim.x + threadIdx.x;
    if (e < E) {
        int d = dst[e];
        int p = atomicAdd(&cursor[d], 1);
        adj_src[p] = src[e];
    }
}

// ---------------- W1/W2 -> MFMA B-fragment-layout fp16 (once) ----------------
__global__ void k_prepw(const float* __restrict__ W1, const float* __restrict__ W2,
                        _Float16* __restrict__ W1f, _Float16* __restrict__ W2f) {
    int i = blockIdx.x * blockDim.x + threadIdx.x;
    if (i < 4096) {
        int ks = i >> 10, rem = i & 1023, nt = rem >> 6, lpos = rem & 63;
        int c = nt * 16 + (lpos & 15);
        int kb = (ks * 4 + (lpos >> 4)) * 8;
        const float4* src = (const float4*)(W1 + (size_t)c * C_DIN + kb);
        float4 f0 = src[0], f1 = src[1];
        _Float16* dst = &W1f[(size_t)i * 8];
        dst[0] = (_Float16)f0.x; dst[1] = (_Float16)f0.y;
        dst[2] = (_Float16)f0.z; dst[3] = (_Float16)f0.w;
        dst[4] = (_Float16)f1.x; dst[5] = (_Float16)f1.y;
        dst[6] = (_Float16)f1.z; dst[7] = (_Float16)f1.w;
    } else if (i < 4096 + 2048) {
        int ii = i - 4096;
        int ks = ii >> 10, rem = ii & 1023, nt = rem >> 6, lpos = rem & 63;
        int c = nt * 16 + (lpos & 15);
        int kb = (ks * 4 + (lpos >> 4)) * 8;
        const float4* src = (const float4*)(W2 + (size_t)c * C_CH + kb);
        float4 f0 = src[0], f1 = src[1];
        _Float16* dst = &W2f[(size_t)ii * 8];
        dst[0] = (_Float16)f0.x; dst[1] = (_Float16)f0.y;
        dst[2] = (_Float16)f0.z; dst[3] = (_Float16)f0.w;
        dst[4] = (_Float16)f1.x; dst[5] = (_Float16)f1.y;
        dst[6] = (_Float16)f1.z; dst[7] = (_Float16)f1.w;
    }
}

// ---------------- layer 1 GEMM (MFMA fp16): h = x @ W1^T, fused a_s1/a_d1 ----------------
__global__ __launch_bounds__(256) void k_gemm1(
    const float* __restrict__ x, const _Float16* __restrict__ W1f,
    const float* __restrict__ att_s, const float* __restrict__ att_d,
    __half* __restrict__ hh_out, float* __restrict__ a_s, float* __restrict__ a_d, int n) {
    __shared__ __align__(16) _Float16 as_[4 * 4 * 64 * 8];  // 16 KB
    int t = threadIdx.x;
    int r0 = blockIdx.x * MBLK;
    {
        int row = t >> 2, q = t & 3;
        int rr = r0 + row;
        int mt = row >> 4, rl = row & 15;
        const float4* xrow = (const float4*)(x + (size_t)rr * C_DIN);
#pragma unroll
        for (int cc = 0; cc < 4; ++cc) {
            int ch = q * 4 + cc;
            float4 f0 = make_float4(0, 0, 0, 0), f1 = make_float4(0, 0, 0, 0);
            if (rr < n) { f0 = xrow[ch * 2]; f1 = xrow[ch * 2 + 1]; }
            int ks = ch >> 2, lg = ch & 3;
            _Float16* dst = &as_[(((ks * 4 + mt) * 64) + (lg * 16 + rl)) * 8];
            dst[0] = (_Float16)f0.x; dst[1] = (_Float16)f0.y;
            dst[2] = (_Float16)f0.z; dst[3] = (_Float16)f0.w;
            dst[4] = (_Float16)f1.x; dst[5] = (_Float16)f1.y;
            dst[6] = (_Float16)f1.z; dst[7] = (_Float16)f1.w;
        }
    }
    __syncthreads();
    int w = t >> 6, l = t & 63;
    const half8* Wv = (const half8*)W1f;
    f32x4 acc[4][4];
#pragma unroll
    for (int mt = 0; mt < 4; ++mt)
#pragma unroll
        for (int nt = 0; nt < 4; ++nt) acc[mt][nt] = (f32x4){0.f, 0.f, 0.f, 0.f};
#pragma unroll
    for (int ks = 0; ks < 4; ++ks) {
        half8 af[4], bf[4];
#pragma unroll
        for (int mt = 0; mt < 4; ++mt)
            af[mt] = *(const half8*)&as_[(((ks * 4 + mt) * 64) + l) * 8];
#pragma unroll
        for (int nt = 0; nt < 4; ++nt)
            bf[nt] = Wv[((ks * 16 + (w * 4 + nt)) * 64) + l];
#pragma unroll
        for (int mt = 0; mt < 4; ++mt)
#pragma unroll
            for (int nt = 0; nt < 4; ++nt)
                acc[mt][nt] = __builtin_amdgcn_mfma_f32_16x16x32_f16(af[mt], bf[nt],
                                                                     acc[mt][nt], 0, 0, 0);
    }
    int cl = l & 15, rg = l >> 4;
    float atv_s[4], atv_d[4];
#pragma unroll
    for (int nt = 0; nt < 4; ++nt) {
        atv_s[nt] = att_s[w * 64 + nt * 16 + cl];
        atv_d[nt] = att_d[w * 64 + nt * 16 + cl];
    }
#pragma unroll
    for (int mt = 0; mt < 4; ++mt) {
#pragma unroll
        for (int r = 0; r < 4; ++r) {
            int rr = r0 + mt * 16 + rg * 4 + r;
            float vs = 0.f, vd = 0.f;
#pragma unroll
            for (int nt = 0; nt < 4; ++nt) {
                float v = acc[mt][nt][r];
                vs += atv_s[nt] * v;
                vd += atv_d[nt] * v;
                if (rr < n)
                    hh_out[(size_t)rr * C_HC + w * 64 + nt * 16 + cl] = __float2half(v);
            }
#pragma unroll
            for (int off = 1; off < 16; off <<= 1) {
                vs += __shfl_xor(vs, off);
                vd += __shfl_xor(vd, off);
            }
            if (cl == 0 && rr < n) { a_s[rr * C_H + w] = vs; a_d[rr * C_H + w] = vd; }
        }
    }
}

// ---------------- layer 1 aggregation: WAVE per node, no LDS, no barriers ----------------
// Lane l: edge-group g=l>>4 (4 edges in flight), channel-slice q=l&15 (16 halves),
// head h=q>>2. Unnormalized exp (logits bounded), self-loop added in group 0.
__global__ __launch_bounds__(256) void k_layer1(
    const int* __restrict__ row_ptr, const int* __restrict__ adj_src,
    const __half* __restrict__ hhlf, const float* __restrict__ a_s,
    const float* __restrict__ a_d, const float* __restrict__ bias1,
    float* __restrict__ h1, int n) {
    int wid = (blockIdx.x * blockDim.x + threadIdx.x) >> 6;
    if (wid >= n) return;
    int l = threadIdx.x & 63, g = l >> 4, q = l & 15, h = q >> 2;
    int d = wid;
    int beg = row_ptr[d], end = row_ptr[d + 1];
    float adh = a_d[d * C_H + h];
    const float4* drow = (const float4*)(hhlf + (size_t)d * C_HC + q * 16);
    float4 d0 = drow[0], d1 = drow[1];
    float acc[16];
#pragma unroll
    for (int i = 0; i < 16; ++i) acc[i] = 0.f;
    float s = 0.f;
    if (g == 0) {
        float ps = expf(lrelu(a_s[d * C_H + h] + adh));
        const __half2* pa = (const __half2*)&d0;
        const __half2* pb = (const __half2*)&d1;
#pragma unroll
        for (int k = 0; k < 4; ++k) {
            float2 a = __half22float2(pa[k]);
            acc[k * 2] += ps * a.x; acc[k * 2 + 1] += ps * a.y;
            float2 b = __half22float2(pb[k]);
            acc[8 + k * 2] += ps * b.x; acc[8 + k * 2 + 1] += ps * b.y;
        }
        s += ps;
    }
    for (int cb = beg; cb < end; cb += 4) {
        int e = cb + g;
        bool act = e < end;
        int j = act ? adj_src[e] : d;
        const float4* jrow = (const float4*)(hhlf + (size_t)j * C_HC + q * 16);
        float4 r0 = jrow[0], r1 = jrow[1];
        float p = act ? expf(lrelu(a_s[j * C_H + h] + adh)) : 0.f;
        const __half2* pa = (const __half2*)&r0;
        const __half2* pb = (const __half2*)&r1;
#pragma unroll
        for (int k = 0; k < 4; ++k) {
            float2 a = __half22float2(pa[k]);
            acc[k * 2] += p * a.x; acc[k * 2 + 1] += p * a.y;
            float2 b = __half22float2(pb[k]);
            acc[8 + k * 2] += p * b.x; acc[8 + k * 2 + 1] += p * b.y;
        }
        s += p;
    }
    // cross-group reduce (sum over the 4 edge groups)
#pragma unroll
    for (int off = 16; off <= 32; off <<= 1) {
#pragma unroll
        for (int i = 0; i < 16; ++i) acc[i] += __shfl_xor(acc[i], off);
        s += __shfl_xor(s, off);
    }
    float inv = 1.f / (s + 1e-16f);
#pragma unroll
    for (int i = 0; i < 16; ++i) acc[i] *= inv;
    // head mean (sum over heads: q bit2 -> xor 4, q bit3 -> xor 8)
#pragma unroll
    for (int off = 4; off <= 8; off <<= 1) {
#pragma unroll
        for (int i = 0; i < 16; ++i) acc[i] += __shfl_xor(acc[i], off);
    }
    if (l < 4) {
#pragma unroll
        for (int i = 0; i < 16; ++i)
            h1[(size_t)d * C_CH + l * 16 + i] =
                fmaxf(acc[i] * 0.25f + bias1[l * 16 + i], 0.f);
    }
}

// ---------------- batch-norm stats ----------------
__global__ void k_bnstats(const float* __restrict__ h1, float* __restrict__ bn, int n) {
    int t = threadIdx.x;
    int c = t & 63, rg = t >> 6;
    float s = 0.f, s2 = 0.f;
    for (int r = blockIdx.x * 4 + rg; r < n; r += gridDim.x * 4) {
        float v = h1[(size_t)r * C_CH + c];
        s += v;
        s2 += v * v;
    }
    __shared__ float ls[256], ls2[256];
    ls[t] = s; ls2[t] = s2;
    __syncthreads();
    if (t < 64) {
        s = ls[t] + ls[t + 64] + ls[t + 128] + ls[t + 192];
        s2 = ls2[t] + ls2[t + 64] + ls2[t + 128] + ls2[t + 192];
        atomicAdd(&bn[c], s);
        atomicAdd(&bn[64 + c], s2);
    }
}

// ---------------- layer 2 GEMM (MFMA fp16): x2 = BN(h1) @ W2^T, fused as2/ad2/nf ----------
__global__ __launch_bounds__(256) void k_gemm2(
    const float* __restrict__ h1, const _Float16* __restrict__ W2f,
    const float* __restrict__ att_s, const float* __restrict__ att_d,
    const float* __restrict__ bn, __half* __restrict__ x2h,
    float* __restrict__ as2, float* __restrict__ ad2, float* __restrict__ nf, int n) {
    __shared__ __align__(16) _Float16 as_[2 * 4 * 64 * 8];  // 8 KB
    __shared__ float nq[64][4];
    int t = threadIdx.x;
    int r0 = blockIdx.x * MBLK;
    {
        int row = t >> 2, q = t & 3;
        int rr = r0 + row;
        int mt = row >> 4, rl = row & 15;
        const float invN = 1.f / (float)n;
        const float4* hrow = (const float4*)(h1 + (size_t)rr * C_CH);
#pragma unroll
        for (int cc = 0; cc < 2; ++cc) {
            int ch = q * 2 + cc;
            float4 f0 = make_float4(0, 0, 0, 0), f1 = make_float4(0, 0, 0, 0);
            if (rr < n) { f0 = hrow[ch * 2]; f1 = hrow[ch * 2 + 1]; }
            float4 s0 = *(const float4*)&bn[ch * 8];
            float4 s1 = *(const float4*)&bn[ch * 8 + 4];
            float4 q0 = *(const float4*)&bn[64 + ch * 8];
            float4 q1 = *(const float4*)&bn[64 + ch * 8 + 4];
            float4 mu0 = make_float4(s0.x * invN, s0.y * invN, s0.z * invN, s0.w * invN);
            float4 mu1 = make_float4(s1.x * invN, s1.y * invN, s1.z * invN, s1.w * invN);
            float4 rs0 = make_float4(rsqrtf(q0.x * invN - mu0.x * mu0.x + 1e-5f),
                                     rsqrtf(q0.y * invN - mu0.y * mu0.y + 1e-5f),
                                     rsqrtf(q0.z * invN - mu0.z * mu0.z + 1e-5f),
                                     rsqrtf(q0.w * invN - mu0.w * mu0.w + 1e-5f));
            float4 rs1 = make_float4(rsqrtf(q1.x * invN - mu1.x * mu1.x + 1e-5f),
                                     rsqrtf(q1.y * invN - mu1.y * mu1.y + 1e-5f),
                                     rsqrtf(q1.z * invN - mu1.z * mu1.z + 1e-5f),
                                     rsqrtf(q1.w * invN - mu1.w * mu1.w + 1e-5f));
            int ks = ch >> 1, lg = ch & 1;  // note: ks<2, each ks covers 4 chunks of 8? no:
            // C_CH=64 -> 8 chunks of 8; frag k-slot = chunk>>2, lane-group = chunk&3
            ks = ch >> 2; lg = ch & 3;
            _Float16* dst = &as_[(((ks * 4 + mt) * 64) + (lg * 16 + rl)) * 8];
            dst[0] = (_Float16)((f0.x - mu0.x) * rs0.x);
            dst[1] = (_Float16)((f0.y - mu0.y) * rs0.y);
            dst[2] = (_Float16)((f0.z - mu0.z) * rs0.z);
            dst[3] = (_Float16)((f0.w - mu0.w) * rs0.w);
            dst[4] = (_Float16)((f1.x - mu1.x) * rs1.x);
            dst[5] = (_Float16)((f1.y - mu1.y) * rs1.y);
            dst[6] = (_Float16)((f1.z - mu1.z) * rs1.z);
            dst[7] = (_Float16)((f1.w - mu1.w) * rs1.w);
        }
    }
    __syncthreads();
    int w = t >> 6, l = t & 63;
    const half8* Wv = (const half8*)W2f;
    f32x4 acc[4][4];
#pragma unroll
    for (int mt = 0; mt < 4; ++mt)
#pragma unroll
        for (int nt = 0; nt < 4; ++nt) acc[mt][nt] = (f32x4){0.f, 0.f, 0.f, 0.f};
#pragma unroll
    for (int ks = 0; ks < 2; ++ks) {
        half8 af[4], bf[4];
#pragma unroll
        for (int mt = 0; mt < 4; ++mt)
            af[mt] = *(const half8*)&as_[(((ks * 4 + mt) * 64) + l) * 8];
#pragma unroll
        for (int nt = 0; nt < 4; ++nt)
            bf[nt] = Wv[((ks * 16 + (w * 4 + nt)) * 64) + l];
#pragma unroll
        for (int mt = 0; mt < 4; ++mt)
#pragma unroll
            for (int nt = 0; nt < 4; ++nt)
                acc[mt][nt] = __builtin_amdgcn_mfma_f32_16x16x32_f16(af[mt], bf[nt],
                                                                     acc[mt][nt], 0, 0, 0);
    }
    int cl = l & 15, rg = l >> 4;
    float atv_s[4], atv_d[4];
#pragma unroll
    for (int nt = 0; nt < 4; ++nt) {
        atv_s[nt] = att_s[w * 64 + nt * 16 + cl];
        atv_d[nt] = att_d[w * 64 + nt * 16 + cl];
    }
#pragma unroll
    for (int mt = 0; mt < 4; ++mt) {
#pragma unroll
        for (int r = 0; r < 4; ++r) {
            int rr = r0 + mt * 16 + rg * 4 + r;
            float vs = 0.f, vd = 0.f, vq = 0.f;
#pragma unroll
            for (int nt = 0; nt < 4; ++nt) {
                float v = acc[mt][nt][r];
                vs += atv_s[nt] * v;
                vd += atv_d[nt] * v;
                vq += v * v;
                if (rr < n)
                    x2h[(size_t)rr * C_HC + w * 64 + nt * 16 + cl] = __float2half(v);
            }
#pragma unroll
            for (int off = 1; off < 16; off <<= 1) {
                vs += __shfl_xor(vs, off);
                vd += __shfl_xor(vd, off);
                vq += __shfl_xor(vq, off);
            }
            if (cl == 0 && rr < n) {
                as2[rr * C_H + w] = vs;
                ad2[rr * C_H + w] = vd;
                nq[mt * 16 + rg * 4 + r][w] = vq;
            }
        }
    }
    __syncthreads();
    if (t < MBLK) {
        int rr = r0 + t;
        if (rr < n) {
            float qq = nq[t][0] + nq[t][1] + nq[t][2] + nq[t][3];
            nf[rr] = fmaxf(sqrtf(qq), 1e-8f);
        }
    }
}

// ---------------- node trust + struct norms ----------------
__global__ void k_trust(const float* __restrict__ sf, const float* __restrict__ Wt,
                        const float* __restrict__ bt, float* __restrict__ trust,
                        float* __restrict__ ns, int n) {
    int i = blockIdx.x * blockDim.x + threadIdx.x;
    if (i >= n) return;
    const float4* r4 = (const float4*)(sf + (size_t)i * C_S);
    const float4* w4 = (const float4*)Wt;
    float d = 0.f, q = 0.f;
#pragma unroll
    for (int k = 0; k < 8; ++k) {
        float4 a = r4[k], w = w4[k];
        d += a.x * w.x + a.y * w.y + a.z * w.z + a.w * w.w;
        q += a.x * a.x + a.y * a.y + a.z * a.z + a.w * a.w;
    }
    trust[i] = 1.f / (1.f + expf(-(d + bt[0])));
    ns[i] = fmaxf(sqrtf(q), 1e-8f);
}

// ---------------- fused layer 2: WAVE per node, no LDS, no barriers ----------------
// Lane l: edge-group g=l>>4, channel-slice q=l&15 (16 halves of the 256-wide row),
// head h=q>>2. Per chunk of 4 edges: group loads its edge's row slice, computes
// feature+struct dots (shfl_xor 1..8 within group), replicates the gate MLP across
// the group, forms p for its own head, accumulates p*row in registers.
__global__ __launch_bounds__(256) void k_fused2(
    const int* __restrict__ row_ptr, const int* __restrict__ adj_src,
    const float* __restrict__ sf, const __half* __restrict__ x2h,
    const float* __restrict__ ns, const float* __restrict__ nf,
    const float* __restrict__ trust, const float* __restrict__ as2,
    const float* __restrict__ ad2, const float* __restrict__ We1,
    const float* __restrict__ be1, const float* __restrict__ We2,
    const float* __restrict__ be2, const float* __restrict__ betas,
    const float* __restrict__ bias2, float* __restrict__ out, int n) {
    int wid = (blockIdx.x * blockDim.x + threadIdx.x) >> 6;
    if (wid >= n) return;
    int l = threadIdx.x & 63, g = l >> 4, q = l & 15, h = q >> 2;
    int d = wid;
    int beg = row_ptr[d], end = row_ptr[d + 1];
    // prologue: dst fragments in registers
    const float4* drow = (const float4*)(x2h + (size_t)d * C_HC + q * 16);
    float4 d0 = drow[0], d1 = drow[1];
    float2 sfd = *(const float2*)(sf + (size_t)d * C_S + q * 2);
    float ad2h = ad2[d * C_H + h];
    float nsd = ns[d], nfd = nf[d], trd = trust[d];
    float b20 = be2[0];
    float bt0 = betas[0], bt1 = betas[1], bt2 = betas[2], bt3 = betas[3], bt4 = betas[4];
    float acc[16];
#pragma unroll
    for (int i = 0; i < 16; ++i) acc[i] = 0.f;
    float s = 0.f;
    for (int cb = beg; cb < end; cb += 4) {
        int e = cb + g;
        bool act = e < end;
        int j = act ? adj_src[e] : d;
        const float4* jrow = (const float4*)(x2h + (size_t)j * C_HC + q * 16);
        float4 r0 = jrow[0], r1 = jrow[1];
        float2 sfj = *(const float2*)(sf + (size_t)j * C_S + q * 2);
        // dots
        float fd = 0.f;
        {
            const __half2* pa = (const __half2*)&r0;
            const __half2* pb = (const __half2*)&d0;
#pragma unroll
            for (int k = 0; k < 4; ++k) {
                float2 a = __half22float2(pa[k]), b = __half22float2(pb[k]);
                fd += a.x * b.x + a.y * b.y;
            }
            const __half2* pc = (const __half2*)&r1;
            const __half2* pd = (const __half2*)&d1;
#pragma unroll
            for (int k = 0; k < 4; ++k) {
                float2 a = __half22float2(pc[k]), b = __half22float2(pd[k]);
                fd += a.x * b.x + a.y * b.y;
            }
        }
        float sd = sfj.x * sfd.x + sfj.y * sfd.y;
#pragma unroll
        for (int off = 1; off < 16; off <<= 1) {
            fd += __shfl_xor(fd, off);
            sd += __shfl_xor(sd, off);
        }
        // gate (replicated across the 16-lane group)
        float p = 0.f;
        if (act) {
            float ss = sd / (nsd * ns[j]);
            float fs = fd / (nfd * nf[j]);
            float agr = ss * fs;
            float con = fabsf(ss - fs);
            float gate = b20;
#pragma unroll
            for (int o = 0; o < 8; ++o) {
                float hdn = We1[o * 4 + 0] * ss + We1[o * 4 + 1] * fs +
                            We1[o * 4 + 2] * agr + We1[o * 4 + 3] * con + be1[o];
                gate += We2[o] * fmaxf(hdn, 0.f);
            }
            float eb = (1.f / (1.f + expf(-gate))) * fmaxf(agr, 0.f);
            float et = sqrtf(fmaxf(trd * trust[j], 0.f));
            float tb = et * fmaxf(0.5f * (ss + fs), 0.f);
            float glog = bt0 * ss + bt1 * fs + bt2 * agr + bt3 * eb + bt4 * tb;
            p = expf(lrelu(as2[j * C_H + h] + ad2h) + glog);
        }
        // accumulate p * row
        {
            const __half2* pa = (const __half2*)&r0;
            const __half2* pb = (const __half2*)&r1;
#pragma unroll
            for (int k = 0; k < 4; ++k) {
                float2 a = __half22float2(pa[k]);
                acc[k * 2] += p * a.x; acc[k * 2 + 1] += p * a.y;
                float2 b = __half22float2(pb[k]);
                acc[8 + k * 2] += p * b.x; acc[8 + k * 2 + 1] += p * b.y;
            }
        }
        s += p;
    }
    // cross-group reduce (sum over edge groups)
#pragma unroll
    for (int off = 16; off <= 32; off <<= 1) {
#pragma unroll
        for (int i = 0; i < 16; ++i) acc[i] += __shfl_xor(acc[i], off);
        s += __shfl_xor(s, off);
    }
    float inv = 1.f / (s + 1e-16f);
#pragma unroll
    for (int i = 0; i < 16; ++i) acc[i] *= inv;
    // head mean (sum over heads: xor 4, xor 8)
#pragma unroll
    for (int off = 4; off <= 8; off <<= 1) {
#pragma unroll
        for (int i = 0; i < 16; ++i) acc[i] += __shfl_xor(acc[i], off);
    }
    if (l < 4) {
#pragma unroll
        for (int i = 0; i < 16; ++i)
            out[(size_t)d * C_CH + l * 16 + i] = acc[i] * 0.25f + bias2[l * 16 + i];
    }
}

static inline size_t al256(size_t x) { return (x + 255) & ~(size_t)255; }

extern "C" void kernel_launch(void* const* d_in, const int* in_sizes, int n_in,
                              void* d_out, int out_size, void* d_ws, size_t ws_size,
                              hipStream_t stream) {
    const float* x      = (const float*)d_in[0];
    const int*   ei     = (const int*)d_in[1];
    const float* sf     = (const float*)d_in[2];
    const float* W1     = (const float*)d_in[3];
    const float* atts1  = (const float*)d_in[4];
    const float* attd1  = (const float*)d_in[5];
    const float* bias1  = (const float*)d_in[6];
    const float* W2     = (const float*)d_in[7];
    const float* atts2  = (const float*)d_in[8];
    const float* attd2  = (const float*)d_in[9];
    const float* bias2  = (const float*)d_in[10];
    const float* Wt     = (const float*)d_in[11];
    const float* bt     = (const float*)d_in[12];
    const float* We1    = (const float*)d_in[13];
    const float* be1    = (const float*)d_in[14];
    const float* We2    = (const float*)d_in[15];
    const float* be2    = (const float*)d_in[16];
    const float* betas  = (const float*)d_in[17];

    const int N = in_sizes[0] / C_DIN;
    const int E = in_sizes[1] / 2;
    const int* srcs = ei;
    const int* dsts = ei + E;

    // workspace carve-up; disjoint-lifetime aliases: x2h reuses hhlf,
    // as2/ad2 reuse a_s1/a_d1
    char* p = (char*)d_ws;
    size_t off = 0;
    auto take = [&](size_t bytes) { char* r = p + off; off = al256(off + bytes); return r; };
    __half* hhlf  = (__half*)take((size_t)N * C_HC * 2);  // layer-1 h (fp16); reused as x2h
    float* h1     = (float*)take((size_t)N * C_CH * 4);
    float* a_s1   = (float*)take((size_t)N * C_H * 4);    // reused as as2
    float* a_d1   = (float*)take((size_t)N * C_H * 4);    // reused as ad2
    float* nf     = (float*)take((size_t)N * 4);
    float* ns     = (float*)take((size_t)N * 4);
    float* trust  = (float*)take((size_t)N * 4);
    int*   deg    = (int*)take((size_t)N * 4);
    int*   rowp   = (int*)take((size_t)(N + 1) * 4);
    int*   cursor = (int*)take((size_t)N * 4);
    int*   adj_s  = (int*)take((size_t)E * 4);
    _Float16* W1f = (_Float16*)take(4096 * 8 * 2);        // W1 in B-frag layout
    _Float16* W2f = (_Float16*)take(2048 * 8 * 2);        // W2 in B-frag layout
    float* bn     = (float*)take(128 * 4);  // [0:64) sum, [64:128) sumsq
    (void)ws_size;
    __half* x2h = hhlf;   // alias: hhlf dead after k_layer1, x2h born in k_gemm2
    float* as2  = a_s1;   // alias: a_s1 dead after k_layer1
    float* ad2  = a_d1;   // alias: a_d1 dead after k_layer1

    hipMemsetAsync(deg, 0, (size_t)N * 4, stream);
    hipMemsetAsync(bn, 0, 128 * 4, stream);

    // weight fragment prep + CSR build
    k_prepw<<<24, 256, 0, stream>>>(W1, W2, W1f, W2f);
    k_count<<<(E + 255) / 256, 256, 0, stream>>>(dsts, deg, E);
    k_scan<<<1, 1024, 0, stream>>>(deg, rowp, cursor, N);
    k_scatter<<<(E + 255) / 256, 256, 0, stream>>>(srcs, dsts, cursor, adj_s, E);

    // layer 1
    k_gemm1<<<(N + MBLK - 1) / MBLK, 256, 0, stream>>>(x, W1f, atts1, attd1, hhlf, a_s1,
                                                       a_d1, N);
    k_layer1<<<(N + 3) / 4, 256, 0, stream>>>(rowp, adj_s, hhlf, a_s1, a_d1, bias1, h1, N);
    k_bnstats<<<128, 256, 0, stream>>>(h1, bn, N);

    // layer 2
    k_gemm2<<<(N + MBLK - 1) / MBLK, 256, 0, stream>>>(h1, W2f, atts2, attd2, bn, x2h,
                                                       as2, ad2, nf, N);
    k_trust<<<(N + 255) / 256, 256, 0, stream>>>(sf, Wt, bt, trust, ns, N);
    k_fused2<<<(N + 3) / 4, 256, 0, stream>>>(rowp, adj_s, sf, x2h, ns, nf, trust, as2, ad2,
                                              We1, be1, We2, be2, betas, bias2,
                                              (float*)d_out, N);
}

// Round 15
// 284.225 us; speedup vs baseline: 1.1979x; 1.0795x over previous
//
#include <hip/hip_runtime.h>
#include <hip/hip_bf16.h>
#include <hip/hip_fp16.h>

// Problem constants (verified against setup_inputs)
#define C_DIN 128
#define C_H 4
#define C_CH 64     // per-head channels (CHID == COUT == 64)
#define C_HC 256    // H * CH
#define C_S 32
#define MBLK 64     // GEMM M-tile (rows per block)

typedef __attribute__((ext_vector_type(8))) _Float16 half8;
typedef __attribute__((ext_vector_type(2))) _Float16 h2f;
typedef __attribute__((ext_vector_type(4))) float f32x4;

__device__ __forceinline__ float lrelu(float x) { return x >= 0.f ? x : 0.2f * x; }

#if __has_builtin(__builtin_amdgcn_fdot2)
__device__ __forceinline__ float dot2acc(h2f a, h2f b, float c) {
    return __builtin_amdgcn_fdot2(a, b, c, false);
}
#else
__device__ __forceinline__ float dot2acc(h2f a, h2f b, float c) {
    return c + (float)a.x * (float)b.x + (float)a.y * (float)b.y;
}
#endif

// ---------------- CSR build ----------------
__global__ void k_count(const int* __restrict__ dst, int* __restrict__ deg, int E) {
    int e = blockIdx.x * blockDim.x + threadIdx.x;
    if (e < E) atomicAdd(&deg[dst[e]], 1);
}

__global__ void k_scan(const int* __restrict__ deg, int* __restrict__ row_ptr,
                       int* __restrict__ cursor, int n) {
    __shared__ int part[1024];
    int t = threadIdx.x;
    const int C = (n + 1023) / 1024;
    int base = t * C;
    int s = 0;
    for (int k = 0; k < C; ++k) {
        int idx = base + k;
        if (idx < n) s += deg[idx];
    }
    part[t] = s;
    __syncthreads();
    for (int off = 1; off < 1024; off <<= 1) {
        int v = (t >= off) ? part[t - off] : 0;
        __syncthreads();
        part[t] += v;
        __syncthreads();
    }
    int run = (t == 0) ? 0 : part[t - 1];
    for (int k = 0; k < C; ++k) {
        int idx = base + k;
        if (idx < n) { row_ptr[idx] = run; cursor[idx] = run; run += deg[idx]; }
    }
    if (t == 1023) row_ptr[n] = run;
}

__global__ void k_scatter(const int* __restrict__ src, const int* __restrict__ dst,
                          int* __restrict__ cursor, int* __restrict__ adj_src, int E) {
    int e = blockIdx.x * blockDim.x + threadIdx.x;
    if (e < E) {
        int d = dst[e];
        int p = atomicAdd(&cursor[d], 1);
        adj_src[p] = src[e];
    }
}

// ---------------- W1/W2 -> MFMA B-fragment-layout fp16 (once) ----------------
__global__ void k_prepw(const float* __restrict__ W1, const float* __restrict__ W2,
                        _Float16* __restrict__ W1f, _Float16* __restrict__ W2f) {
    int i = blockIdx.x * blockDim.x + threadIdx.x;
    if (i < 4096) {
        int ks = i >> 10, rem = i & 1023, nt = rem >> 6, lpos = rem & 63;
        int c = nt * 16 + (lpos & 15);
        int kb = (ks * 4 + (lpos >> 4)) * 8;
        const float4* src = (const float4*)(W1 + (size_t)c * C_DIN + kb);
        float4 f0 = src[0], f1 = src[1];
        _Float16* dst = &W1f[(size_t)i * 8];
        dst[0] = (_Float16)f0.x; dst[1] = (_Float16)f0.y;
        dst[2] = (_Float16)f0.z; dst[3] = (_Float16)f0.w;
        dst[4] = (_Float16)f1.x; dst[5] = (_Float16)f1.y;
        dst[6] = (_Float16)f1.z; dst[7] = (_Float16)f1.w;
    } else if (i < 4096 + 2048) {
        int ii = i - 4096;
        int ks = ii >> 10, rem = ii & 1023, nt = rem >> 6, lpos = rem & 63;
        int c = nt * 16 + (lpos & 15);
        int kb = (ks * 4 + (lpos >> 4)) * 8;
        const float4* src = (const float4*)(W2 + (size_t)c * C_CH + kb);
        float4 f0 = src[0], f1 = src[1];
        _Float16* dst = &W2f[(size_t)ii * 8];
        dst[0] = (_Float16)f0.x; dst[1] = (_Float16)f0.y;
        dst[2] = (_Float16)f0.z; dst[3] = (_Float16)f0.w;
        dst[4] = (_Float16)f1.x; dst[5] = (_Float16)f1.y;
        dst[6] = (_Float16)f1.z; dst[7] = (_Float16)f1.w;
    }
}

// ---------------- layer 1 GEMM (MFMA fp16): h = x @ W1^T, fused a_s1/a_d1 ----------------
__global__ __launch_bounds__(256) void k_gemm1(
    const float* __restrict__ x, const _Float16* __restrict__ W1f,
    const float* __restrict__ att_s, const float* __restrict__ att_d,
    __half* __restrict__ hh_out, float* __restrict__ a_s, float* __restrict__ a_d, int n) {
    __shared__ __align__(16) _Float16 as_[4 * 4 * 64 * 8];  // 16 KB
    int t = threadIdx.x;
    int r0 = blockIdx.x * MBLK;
    {
        int row = t >> 2, q = t & 3;
        int rr = r0 + row;
        int mt = row >> 4, rl = row & 15;
        const float4* xrow = (const float4*)(x + (size_t)rr * C_DIN);
#pragma unroll
        for (int cc = 0; cc < 4; ++cc) {
            int ch = q * 4 + cc;
            float4 f0 = make_float4(0, 0, 0, 0), f1 = make_float4(0, 0, 0, 0);
            if (rr < n) { f0 = xrow[ch * 2]; f1 = xrow[ch * 2 + 1]; }
            int ks = ch >> 2, lg = ch & 3;
            _Float16* dst = &as_[(((ks * 4 + mt) * 64) + (lg * 16 + rl)) * 8];
            dst[0] = (_Float16)f0.x; dst[1] = (_Float16)f0.y;
            dst[2] = (_Float16)f0.z; dst[3] = (_Float16)f0.w;
            dst[4] = (_Float16)f1.x; dst[5] = (_Float16)f1.y;
            dst[6] = (_Float16)f1.z; dst[7] = (_Float16)f1.w;
        }
    }
    __syncthreads();
    int w = t >> 6, l = t & 63;
    const half8* Wv = (const half8*)W1f;
    f32x4 acc[4][4];
#pragma unroll
    for (int mt = 0; mt < 4; ++mt)
#pragma unroll
        for (int nt = 0; nt < 4; ++nt) acc[mt][nt] = (f32x4){0.f, 0.f, 0.f, 0.f};
#pragma unroll
    for (int ks = 0; ks < 4; ++ks) {
        half8 af[4], bf[4];
#pragma unroll
        for (int mt = 0; mt < 4; ++mt)
            af[mt] = *(const half8*)&as_[(((ks * 4 + mt) * 64) + l) * 8];
#pragma unroll
        for (int nt = 0; nt < 4; ++nt)
            bf[nt] = Wv[((ks * 16 + (w * 4 + nt)) * 64) + l];
#pragma unroll
        for (int mt = 0; mt < 4; ++mt)
#pragma unroll
            for (int nt = 0; nt < 4; ++nt)
                acc[mt][nt] = __builtin_amdgcn_mfma_f32_16x16x32_f16(af[mt], bf[nt],
                                                                     acc[mt][nt], 0, 0, 0);
    }
    int cl = l & 15, rg = l >> 4;
    float atv_s[4], atv_d[4];
#pragma unroll
    for (int nt = 0; nt < 4; ++nt) {
        atv_s[nt] = att_s[w * 64 + nt * 16 + cl];
        atv_d[nt] = att_d[w * 64 + nt * 16 + cl];
    }
#pragma unroll
    for (int mt = 0; mt < 4; ++mt) {
#pragma unroll
        for (int r = 0; r < 4; ++r) {
            int rr = r0 + mt * 16 + rg * 4 + r;
            float vs = 0.f, vd = 0.f;
#pragma unroll
            for (int nt = 0; nt < 4; ++nt) {
                float v = acc[mt][nt][r];
                vs += atv_s[nt] * v;
                vd += atv_d[nt] * v;
                if (rr < n)
                    hh_out[(size_t)rr * C_HC + w * 64 + nt * 16 + cl] = __float2half(v);
            }
#pragma unroll
            for (int off = 1; off < 16; off <<= 1) {
                vs += __shfl_xor(vs, off);
                vd += __shfl_xor(vd, off);
            }
            if (cl == 0 && rr < n) { a_s[rr * C_H + w] = vs; a_d[rr * C_H + w] = vd; }
        }
    }
}

// ---------------- layer 1 aggregation: wave/node, depth-2 prefetch pipeline ------------
__global__ __launch_bounds__(256) void k_layer1(
    const int* __restrict__ row_ptr, const int* __restrict__ adj_src,
    const __half* __restrict__ hhlf, const float* __restrict__ a_s,
    const float* __restrict__ a_d, const float* __restrict__ bias1,
    float* __restrict__ h1, int n) {
    int wid = (blockIdx.x * blockDim.x + threadIdx.x) >> 6;
    if (wid >= n) return;
    int l = threadIdx.x & 63, g = l >> 4, q = l & 15, h = q >> 2;
    int d = wid;
    int beg = row_ptr[d], end = row_ptr[d + 1];
    float adh = a_d[d * C_H + h];
    const float4* drow = (const float4*)(hhlf + (size_t)d * C_HC + q * 16);
    float4 d0 = drow[0], d1 = drow[1];
    float acc[16];
#pragma unroll
    for (int i = 0; i < 16; ++i) acc[i] = 0.f;
    float s = 0.f;
    if (g == 0) {
        float ps = expf(lrelu(a_s[d * C_H + h] + adh));
        const __half2* pa = (const __half2*)&d0;
        const __half2* pb = (const __half2*)&d1;
#pragma unroll
        for (int k = 0; k < 4; ++k) {
            float2 a = __half22float2(pa[k]);
            acc[k * 2] += ps * a.x; acc[k * 2 + 1] += ps * a.y;
            float2 b = __half22float2(pb[k]);
            acc[8 + k * 2] += ps * b.x; acc[8 + k * 2 + 1] += ps * b.y;
        }
        s += ps;
    }
    // prefetch chunk 0
    bool act = (beg + g) < end;
    int j = act ? adj_src[beg + g] : d;
    const float4* jr = (const float4*)(hhlf + (size_t)j * C_HC + q * 16);
    float4 r0 = jr[0], r1 = jr[1];
    float asj = a_s[j * C_H + h];
    for (int cb = beg; cb < end; cb += 4) {
        // prefetch next chunk
        int en = cb + 4 + g;
        bool actn = en < end;
        int jn = actn ? adj_src[en] : d;
        const float4* jrn = (const float4*)(hhlf + (size_t)jn * C_HC + q * 16);
        float4 nr0 = jrn[0], nr1 = jrn[1];
        float asn = a_s[jn * C_H + h];
        // compute current
        float p = act ? expf(lrelu(asj + adh)) : 0.f;
        const __half2* pa = (const __half2*)&r0;
        const __half2* pb = (const __half2*)&r1;
#pragma unroll
        for (int k = 0; k < 4; ++k) {
            float2 a = __half22float2(pa[k]);
            acc[k * 2] += p * a.x; acc[k * 2 + 1] += p * a.y;
            float2 b = __half22float2(pb[k]);
            acc[8 + k * 2] += p * b.x; acc[8 + k * 2 + 1] += p * b.y;
        }
        s += p;
        act = actn; r0 = nr0; r1 = nr1; asj = asn;
    }
    // cross-group reduce
#pragma unroll
    for (int off = 16; off <= 32; off <<= 1) {
#pragma unroll
        for (int i = 0; i < 16; ++i) acc[i] += __shfl_xor(acc[i], off);
        s += __shfl_xor(s, off);
    }
    float inv = 1.f / (s + 1e-16f);
#pragma unroll
    for (int i = 0; i < 16; ++i) acc[i] *= inv;
    // head mean
#pragma unroll
    for (int off = 4; off <= 8; off <<= 1) {
#pragma unroll
        for (int i = 0; i < 16; ++i) acc[i] += __shfl_xor(acc[i], off);
    }
    if (l < 4) {
#pragma unroll
        for (int i = 0; i < 16; ++i)
            h1[(size_t)d * C_CH + l * 16 + i] =
                fmaxf(acc[i] * 0.25f + bias1[l * 16 + i], 0.f);
    }
}

// ---------------- batch-norm stats ----------------
__global__ void k_bnstats(const float* __restrict__ h1, float* __restrict__ bn, int n) {
    int t = threadIdx.x;
    int c = t & 63, rg = t >> 6;
    float s = 0.f, s2 = 0.f;
    for (int r = blockIdx.x * 4 + rg; r < n; r += gridDim.x * 4) {
        float v = h1[(size_t)r * C_CH + c];
        s += v;
        s2 += v * v;
    }
    __shared__ float ls[256], ls2[256];
    ls[t] = s; ls2[t] = s2;
    __syncthreads();
    if (t < 64) {
        s = ls[t] + ls[t + 64] + ls[t + 128] + ls[t + 192];
        s2 = ls2[t] + ls2[t + 64] + ls2[t + 128] + ls2[t + 192];
        atomicAdd(&bn[c], s);
        atomicAdd(&bn[64 + c], s2);
    }
}

// ---------------- layer 2 GEMM (MFMA fp16): x2 = BN(h1) @ W2^T, fused as2/ad2/nf ----------
__global__ __launch_bounds__(256) void k_gemm2(
    const float* __restrict__ h1, const _Float16* __restrict__ W2f,
    const float* __restrict__ att_s, const float* __restrict__ att_d,
    const float* __restrict__ bn, __half* __restrict__ x2h,
    float* __restrict__ as2, float* __restrict__ ad2, float* __restrict__ nf, int n) {
    __shared__ __align__(16) _Float16 as_[2 * 4 * 64 * 8];  // 8 KB
    __shared__ float nq[64][4];
    int t = threadIdx.x;
    int r0 = blockIdx.x * MBLK;
    {
        int row = t >> 2, q = t & 3;
        int rr = r0 + row;
        int mt = row >> 4, rl = row & 15;
        const float invN = 1.f / (float)n;
        const float4* hrow = (const float4*)(h1 + (size_t)rr * C_CH);
#pragma unroll
        for (int cc = 0; cc < 2; ++cc) {
            int ch = q * 2 + cc;
            float4 f0 = make_float4(0, 0, 0, 0), f1 = make_float4(0, 0, 0, 0);
            if (rr < n) { f0 = hrow[ch * 2]; f1 = hrow[ch * 2 + 1]; }
            float4 s0 = *(const float4*)&bn[ch * 8];
            float4 s1 = *(const float4*)&bn[ch * 8 + 4];
            float4 q0 = *(const float4*)&bn[64 + ch * 8];
            float4 q1 = *(const float4*)&bn[64 + ch * 8 + 4];
            float4 mu0 = make_float4(s0.x * invN, s0.y * invN, s0.z * invN, s0.w * invN);
            float4 mu1 = make_float4(s1.x * invN, s1.y * invN, s1.z * invN, s1.w * invN);
            float4 rs0 = make_float4(rsqrtf(q0.x * invN - mu0.x * mu0.x + 1e-5f),
                                     rsqrtf(q0.y * invN - mu0.y * mu0.y + 1e-5f),
                                     rsqrtf(q0.z * invN - mu0.z * mu0.z + 1e-5f),
                                     rsqrtf(q0.w * invN - mu0.w * mu0.w + 1e-5f));
            float4 rs1 = make_float4(rsqrtf(q1.x * invN - mu1.x * mu1.x + 1e-5f),
                                     rsqrtf(q1.y * invN - mu1.y * mu1.y + 1e-5f),
                                     rsqrtf(q1.z * invN - mu1.z * mu1.z + 1e-5f),
                                     rsqrtf(q1.w * invN - mu1.w * mu1.w + 1e-5f));
            int ks = ch >> 2, lg = ch & 3;
            _Float16* dst = &as_[(((ks * 4 + mt) * 64) + (lg * 16 + rl)) * 8];
            dst[0] = (_Float16)((f0.x - mu0.x) * rs0.x);
            dst[1] = (_Float16)((f0.y - mu0.y) * rs0.y);
            dst[2] = (_Float16)((f0.z - mu0.z) * rs0.z);
            dst[3] = (_Float16)((f0.w - mu0.w) * rs0.w);
            dst[4] = (_Float16)((f1.x - mu1.x) * rs1.x);
            dst[5] = (_Float16)((f1.y - mu1.y) * rs1.y);
            dst[6] = (_Float16)((f1.z - mu1.z) * rs1.z);
            dst[7] = (_Float16)((f1.w - mu1.w) * rs1.w);
        }
    }
    __syncthreads();
    int w = t >> 6, l = t & 63;
    const half8* Wv = (const half8*)W2f;
    f32x4 acc[4][4];
#pragma unroll
    for (int mt = 0; mt < 4; ++mt)
#pragma unroll
        for (int nt = 0; nt < 4; ++nt) acc[mt][nt] = (f32x4){0.f, 0.f, 0.f, 0.f};
#pragma unroll
    for (int ks = 0; ks < 2; ++ks) {
        half8 af[4], bf[4];
#pragma unroll
        for (int mt = 0; mt < 4; ++mt)
            af[mt] = *(const half8*)&as_[(((ks * 4 + mt) * 64) + l) * 8];
#pragma unroll
        for (int nt = 0; nt < 4; ++nt)
            bf[nt] = Wv[((ks * 16 + (w * 4 + nt)) * 64) + l];
#pragma unroll
        for (int mt = 0; mt < 4; ++mt)
#pragma unroll
            for (int nt = 0; nt < 4; ++nt)
                acc[mt][nt] = __builtin_amdgcn_mfma_f32_16x16x32_f16(af[mt], bf[nt],
                                                                     acc[mt][nt], 0, 0, 0);
    }
    int cl = l & 15, rg = l >> 4;
    float atv_s[4], atv_d[4];
#pragma unroll
    for (int nt = 0; nt < 4; ++nt) {
        atv_s[nt] = att_s[w * 64 + nt * 16 + cl];
        atv_d[nt] = att_d[w * 64 + nt * 16 + cl];
    }
#pragma unroll
    for (int mt = 0; mt < 4; ++mt) {
#pragma unroll
        for (int r = 0; r < 4; ++r) {
            int rr = r0 + mt * 16 + rg * 4 + r;
            float vs = 0.f, vd = 0.f, vq = 0.f;
#pragma unroll
            for (int nt = 0; nt < 4; ++nt) {
                float v = acc[mt][nt][r];
                vs += atv_s[nt] * v;
                vd += atv_d[nt] * v;
                vq += v * v;
                if (rr < n)
                    x2h[(size_t)rr * C_HC + w * 64 + nt * 16 + cl] = __float2half(v);
            }
#pragma unroll
            for (int off = 1; off < 16; off <<= 1) {
                vs += __shfl_xor(vs, off);
                vd += __shfl_xor(vd, off);
                vq += __shfl_xor(vq, off);
            }
            if (cl == 0 && rr < n) {
                as2[rr * C_H + w] = vs;
                ad2[rr * C_H + w] = vd;
                nq[mt * 16 + rg * 4 + r][w] = vq;
            }
        }
    }
    __syncthreads();
    if (t < MBLK) {
        int rr = r0 + t;
        if (rr < n) {
            float qq = nq[t][0] + nq[t][1] + nq[t][2] + nq[t][3];
            nf[rr] = fmaxf(sqrtf(qq), 1e-8f);
        }
    }
}

// ---------------- node trust + struct norms -> packed meta (ns, nf, trust, 0) ----------
__global__ void k_trust(const float* __restrict__ sf, const float* __restrict__ Wt,
                        const float* __restrict__ bt, const float* __restrict__ nf,
                        float* __restrict__ meta, int n) {
    int i = blockIdx.x * blockDim.x + threadIdx.x;
    if (i >= n) return;
    const float4* r4 = (const float4*)(sf + (size_t)i * C_S);
    const float4* w4 = (const float4*)Wt;
    float d = 0.f, q = 0.f;
#pragma unroll
    for (int k = 0; k < 8; ++k) {
        float4 a = r4[k], w = w4[k];
        d += a.x * w.x + a.y * w.y + a.z * w.z + a.w * w.w;
        q += a.x * a.x + a.y * a.y + a.z * a.z + a.w * a.w;
    }
    float tr = 1.f / (1.f + expf(-(d + bt[0])));
    float nsv = fmaxf(sqrtf(q), 1e-8f);
    *(float4*)&meta[(size_t)i * 4] = make_float4(nsv, nf[i], tr, 0.f);
}

// ---------------- fused layer 2: wave/node, depth-2 prefetch, fdot2 ----------------
__global__ __launch_bounds__(256) void k_fused2(
    const int* __restrict__ row_ptr, const int* __restrict__ adj_src,
    const float* __restrict__ sf, const __half* __restrict__ x2h,
    const float* __restrict__ meta, const float* __restrict__ as2,
    const float* __restrict__ ad2, const float* __restrict__ We1,
    const float* __restrict__ be1, const float* __restrict__ We2,
    const float* __restrict__ be2, const float* __restrict__ betas,
    const float* __restrict__ bias2, float* __restrict__ out, int n) {
    int wid = (blockIdx.x * blockDim.x + threadIdx.x) >> 6;
    if (wid >= n) return;
    int l = threadIdx.x & 63, g = l >> 4, q = l & 15, h = q >> 2;
    int d = wid;
    int beg = row_ptr[d], end = row_ptr[d + 1];
    const float4* drow = (const float4*)(x2h + (size_t)d * C_HC + q * 16);
    float4 d0 = drow[0], d1 = drow[1];
    float2 sfd = *(const float2*)(sf + (size_t)d * C_S + q * 2);
    float ad2h = ad2[d * C_H + h];
    float4 md = *(const float4*)&meta[(size_t)d * 4];
    float nsd = md.x, nfd = md.y, trd = md.z;
    float b20 = be2[0];
    float bt0 = betas[0], bt1 = betas[1], bt2 = betas[2], bt3 = betas[3], bt4 = betas[4];
    float acc[16];
#pragma unroll
    for (int i = 0; i < 16; ++i) acc[i] = 0.f;
    float s = 0.f;
    // prefetch chunk 0
    bool act = (beg + g) < end;
    int j = act ? adj_src[beg + g] : d;
    const float4* jr0 = (const float4*)(x2h + (size_t)j * C_HC + q * 16);
    float4 r0 = jr0[0], r1 = jr0[1];
    float2 sfj = *(const float2*)(sf + (size_t)j * C_S + q * 2);
    float4 mj = *(const float4*)&meta[(size_t)j * 4];
    float4 asj = *(const float4*)&as2[j * C_H];
    for (int cb = beg; cb < end; cb += 4) {
        // prefetch next chunk
        int en = cb + 4 + g;
        bool actn = en < end;
        int jn = actn ? adj_src[en] : d;
        const float4* jrn = (const float4*)(x2h + (size_t)jn * C_HC + q * 16);
        float4 nr0 = jrn[0], nr1 = jrn[1];
        float2 nsfj = *(const float2*)(sf + (size_t)jn * C_S + q * 2);
        float4 nmj = *(const float4*)&meta[(size_t)jn * 4];
        float4 nasj = *(const float4*)&as2[jn * C_H];
        // ---- compute current chunk ----
        float fd = 0.f;
        {
            const h2f* pa = (const h2f*)&r0;
            const h2f* pb = (const h2f*)&d0;
#pragma unroll
            for (int k = 0; k < 4; ++k) fd = dot2acc(pa[k], pb[k], fd);
            const h2f* pc = (const h2f*)&r1;
            const h2f* pd = (const h2f*)&d1;
#pragma unroll
            for (int k = 0; k < 4; ++k) fd = dot2acc(pc[k], pd[k], fd);
        }
        float sd = sfj.x * sfd.x + sfj.y * sfd.y;
#pragma unroll
        for (int off = 1; off < 16; off <<= 1) {
            fd += __shfl_xor(fd, off);
            sd += __shfl_xor(sd, off);
        }
        float p = 0.f;
        if (act) {
            float ss = sd / (nsd * mj.x);
            float fs = fd / (nfd * mj.y);
            float agr = ss * fs;
            float con = fabsf(ss - fs);
            float gate = b20;
#pragma unroll
            for (int o = 0; o < 8; ++o) {
                float hdn = We1[o * 4 + 0] * ss + We1[o * 4 + 1] * fs +
                            We1[o * 4 + 2] * agr + We1[o * 4 + 3] * con + be1[o];
                gate += We2[o] * fmaxf(hdn, 0.f);
            }
            float eb = (1.f / (1.f + expf(-gate))) * fmaxf(agr, 0.f);
            float et = sqrtf(fmaxf(trd * mj.z, 0.f));
            float tb = et * fmaxf(0.5f * (ss + fs), 0.f);
            float glog = bt0 * ss + bt1 * fs + bt2 * agr + bt3 * eb + bt4 * tb;
            float ash = (h == 0) ? asj.x : (h == 1) ? asj.y : (h == 2) ? asj.z : asj.w;
            p = expf(lrelu(ash + ad2h) + glog);
        }
        {
            const __half2* pa = (const __half2*)&r0;
            const __half2* pb = (const __half2*)&r1;
#pragma unroll
            for (int k = 0; k < 4; ++k) {
                float2 a = __half22float2(pa[k]);
                acc[k * 2] += p * a.x; acc[k * 2 + 1] += p * a.y;
                float2 b = __half22float2(pb[k]);
                acc[8 + k * 2] += p * b.x; acc[8 + k * 2 + 1] += p * b.y;
            }
        }
        s += p;
        // rotate
        act = actn; r0 = nr0; r1 = nr1; sfj = nsfj; mj = nmj; asj = nasj;
    }
    // cross-group reduce
#pragma unroll
    for (int off = 16; off <= 32; off <<= 1) {
#pragma unroll
        for (int i = 0; i < 16; ++i) acc[i] += __shfl_xor(acc[i], off);
        s += __shfl_xor(s, off);
    }
    float inv = 1.f / (s + 1e-16f);
#pragma unroll
    for (int i = 0; i < 16; ++i) acc[i] *= inv;
    // head mean
#pragma unroll
    for (int off = 4; off <= 8; off <<= 1) {
#pragma unroll
        for (int i = 0; i < 16; ++i) acc[i] += __shfl_xor(acc[i], off);
    }
    if (l < 4) {
#pragma unroll
        for (int i = 0; i < 16; ++i)
            out[(size_t)d * C_CH + l * 16 + i] = acc[i] * 0.25f + bias2[l * 16 + i];
    }
}

static inline size_t al256(size_t x) { return (x + 255) & ~(size_t)255; }

extern "C" void kernel_launch(void* const* d_in, const int* in_sizes, int n_in,
                              void* d_out, int out_size, void* d_ws, size_t ws_size,
                              hipStream_t stream) {
    const float* x      = (const float*)d_in[0];
    const int*   ei     = (const int*)d_in[1];
    const float* sf     = (const float*)d_in[2];
    const float* W1     = (const float*)d_in[3];
    const float* atts1  = (const float*)d_in[4];
    const float* attd1  = (const float*)d_in[5];
    const float* bias1  = (const float*)d_in[6];
    const float* W2     = (const float*)d_in[7];
    const float* atts2  = (const float*)d_in[8];
    const float* attd2  = (const float*)d_in[9];
    const float* bias2  = (const float*)d_in[10];
    const float* Wt     = (const float*)d_in[11];
    const float* bt     = (const float*)d_in[12];
    const float* We1    = (const float*)d_in[13];
    const float* be1    = (const float*)d_in[14];
    const float* We2    = (const float*)d_in[15];
    const float* be2    = (const float*)d_in[16];
    const float* betas  = (const float*)d_in[17];

    const int N = in_sizes[0] / C_DIN;
    const int E = in_sizes[1] / 2;
    const int* srcs = ei;
    const int* dsts = ei + E;

    // workspace carve-up; disjoint-lifetime aliases: x2h reuses hhlf,
    // as2/ad2 reuse a_s1/a_d1
    char* p = (char*)d_ws;
    size_t off = 0;
    auto take = [&](size_t bytes) { char* r = p + off; off = al256(off + bytes); return r; };
    __half* hhlf  = (__half*)take((size_t)N * C_HC * 2);  // layer-1 h (fp16); reused as x2h
    float* h1     = (float*)take((size_t)N * C_CH * 4);
    float* a_s1   = (float*)take((size_t)N * C_H * 4);    // reused as as2
    float* a_d1   = (float*)take((size_t)N * C_H * 4);    // reused as ad2
    float* nf     = (float*)take((size_t)N * 4);
    float* meta   = (float*)take((size_t)N * 4 * 4);      // (ns, nf, trust, 0) per node
    int*   deg    = (int*)take((size_t)N * 4);
    int*   rowp   = (int*)take((size_t)(N + 1) * 4);
    int*   cursor = (int*)take((size_t)N * 4);
    int*   adj_s  = (int*)take((size_t)E * 4);
    _Float16* W1f = (_Float16*)take(4096 * 8 * 2);        // W1 in B-frag layout
    _Float16* W2f = (_Float16*)take(2048 * 8 * 2);        // W2 in B-frag layout
    float* bn     = (float*)take(128 * 4);  // [0:64) sum, [64:128) sumsq
    (void)ws_size;
    __half* x2h = hhlf;   // alias: hhlf dead after k_layer1, x2h born in k_gemm2
    float* as2  = a_s1;   // alias: a_s1 dead after k_layer1
    float* ad2  = a_d1;   // alias: a_d1 dead after k_layer1

    hipMemsetAsync(deg, 0, (size_t)N * 4, stream);
    hipMemsetAsync(bn, 0, 128 * 4, stream);

    // weight fragment prep + CSR build
    k_prepw<<<24, 256, 0, stream>>>(W1, W2, W1f, W2f);
    k_count<<<(E + 255) / 256, 256, 0, stream>>>(dsts, deg, E);
    k_scan<<<1, 1024, 0, stream>>>(deg, rowp, cursor, N);
    k_scatter<<<(E + 255) / 256, 256, 0, stream>>>(srcs, dsts, cursor, adj_s, E);

    // layer 1
    k_gemm1<<<(N + MBLK - 1) / MBLK, 256, 0, stream>>>(x, W1f, atts1, attd1, hhlf, a_s1,
                                                       a_d1, N);
    k_layer1<<<(N + 3) / 4, 256, 0, stream>>>(rowp, adj_s, hhlf, a_s1, a_d1, bias1, h1, N);
    k_bnstats<<<128, 256, 0, stream>>>(h1, bn, N);

    // layer 2
    k_gemm2<<<(N + MBLK - 1) / MBLK, 256, 0, stream>>>(h1, W2f, atts2, attd2, bn, x2h,
                                                       as2, ad2, nf, N);
    k_trust<<<(N + 255) / 256, 256, 0, stream>>>(sf, Wt, bt, nf, meta, N);
    k_fused2<<<(N + 3) / 4, 256, 0, stream>>>(rowp, adj_s, sf, x2h, meta, as2, ad2,
                                              We1, be1, We2, be2, betas, bias2,
                                              (float*)d_out, N);
}